// Round 1
// baseline (446.305 us; speedup 1.0000x reference)
//
#include <hip/hip_runtime.h>
#include <hip/hip_bf16.h>

// GroupedQueryAttention: B=2,S=2048,D=2048,H=16,G=4,HD=128, causal, rmsnorm+rope.
// Inputs fp32; OUTPUT fp32. Internal compute bf16 MFMA / fp32 accumulate.
// R10: attn occupancy fix — split 4-head blocks into 2-head blocks and drop the
// paired-q-tile loop: grid 512 -> 2048 blocks (2 -> ~6 blocks/CU). Long q-tiles
// (qt=127-blockIdx.x) dispatch first so variable block durations pack well.
// ws (58.7 MB): qb | kb | vb | vtb | ctx(=xb alias) | wqb(=wob) | wkb | wvb

typedef __bf16 bf16_t;
using bf16x4 = __attribute__((ext_vector_type(4))) __bf16;
using bf16x8 = __attribute__((ext_vector_type(8))) __bf16;
using f32x4  = __attribute__((ext_vector_type(4))) float;

#define LDSCP16(gp, lp)                                                       \
  __builtin_amdgcn_global_load_lds(                                           \
      (__attribute__((address_space(1))) void*)(gp),                          \
      (__attribute__((address_space(3))) void*)(lp), 16, 0, 0)

// ---------- merged fp32 -> bf16 casts: x | Wq | Wk | Wv ----------
__global__ __launch_bounds__(256) void cast_all(
    const float* __restrict__ x, const float* __restrict__ wq,
    const float* __restrict__ wk, const float* __restrict__ wv,
    bf16_t* __restrict__ xb, bf16_t* __restrict__ wqb,
    bf16_t* __restrict__ wkb, bf16_t* __restrict__ wvb) {
  int blk = blockIdx.x;
  const float* s;
  bf16_t* d;
  size_t base;
  if (blk < 4096)      { s = x;  d = xb;  base = blk; }
  else if (blk < 6144) { s = wq; d = wqb; base = blk - 4096; }
  else if (blk < 6656) { s = wk; d = wkb; base = blk - 6144; }
  else                 { s = wv; d = wvb; base = blk - 6656; }
  size_t i = base * 256 + threadIdx.x;
  const float* g = s + i * 8;
  f32x4 u0 = *(const f32x4*)g;
  f32x4 u1 = *(const f32x4*)(g + 4);
  bf16x8 v;
  v[0] = (bf16_t)u0[0]; v[1] = (bf16_t)u0[1]; v[2] = (bf16_t)u0[2]; v[3] = (bf16_t)u0[3];
  v[4] = (bf16_t)u1[0]; v[5] = (bf16_t)u1[1]; v[6] = (bf16_t)u1[2]; v[7] = (bf16_t)u1[3];
  *(bf16x8*)(d + i * 8) = v;
}

// ---------- single fp32 -> bf16 cast (Wo, after qkv frees wqb) ----------
__global__ __launch_bounds__(256) void cast_f32_bf16(const float* __restrict__ src,
                                                     bf16_t* __restrict__ dst) {
  size_t i = (size_t)blockIdx.x * 256 + threadIdx.x;
  const float* g = src + i * 8;
  f32x4 u0 = *(const f32x4*)g;
  f32x4 u1 = *(const f32x4*)(g + 4);
  bf16x8 v;
  v[0] = (bf16_t)u0[0]; v[1] = (bf16_t)u0[1]; v[2] = (bf16_t)u0[2]; v[3] = (bf16_t)u0[3];
  v[4] = (bf16_t)u1[0]; v[5] = (bf16_t)u1[1]; v[6] = (bf16_t)u1[2]; v[7] = (bf16_t)u1[3];
  *(bf16x8*)(dst + i * 8) = v;
}

// ---------- 128x128-tile GEMM mainloop: C = A[M,K] * B[N,K]^T (both bf16) ----
// global_load_lds w16, source-side XOR chunk swizzle; frag reads 2-way (free).
__device__ __forceinline__ void gemm_tile(const bf16_t* __restrict__ A,
                                          const bf16_t* __restrict__ B, int K,
                                          int m0, int n0, bf16_t* As, bf16_t* Bs,
                                          f32x4 acc[4][4]) {
  const int tid = threadIdx.x;
  const int lane = tid & 63, w = tid >> 6;
  const int quad = lane >> 4, l16 = lane & 15;
  const int wm = (w >> 1) * 64, wn = (w & 1) * 64;
  char* AsB = (char*)As;
  char* BsB = (char*)Bs;
  const int nkt = K >> 6;
  for (int kt = 0; kt < nkt; ++kt) {
#pragma unroll
    for (int i = 0; i < 4; ++i) {
      int s = i * 256 + tid;
      int row = s >> 3, ch = s & 7;
      int sc = ch ^ (row & 7);
      LDSCP16(A + (size_t)(m0 + row) * K + kt * 64 + sc * 8, As + s * 8);
      LDSCP16(B + (size_t)(n0 + row) * K + kt * 64 + sc * 8, Bs + s * 8);
    }
    __syncthreads();
#pragma unroll
    for (int kk = 0; kk < 2; ++kk) {
      bf16x8 af[4], bfv[4];
#pragma unroll
      for (int i = 0; i < 4; ++i) {
        int ra = wm + i * 16 + l16;
        af[i] = *(const bf16x8*)(AsB + ra * 128 + (((kk * 4 + quad) ^ (ra & 7)) << 4));
        int rb = wn + i * 16 + l16;
        bfv[i] = *(const bf16x8*)(BsB + rb * 128 + (((kk * 4 + quad) ^ (rb & 7)) << 4));
      }
#pragma unroll
      for (int im = 0; im < 4; ++im)
#pragma unroll
        for (int in_ = 0; in_ < 4; ++in_)
          acc[im][in_] = __builtin_amdgcn_mfma_f32_16x16x32_bf16(
              af[im], bfv[in_], acc[im][in_], 0, 0, 0);
    }
    __syncthreads();
  }
}

// ---------- fused QKV projection; writes head-major [B,Hn,S,HD] bf16 ----------
__global__ __launch_bounds__(256) void qkv_gemm(
    const bf16_t* __restrict__ x, const bf16_t* __restrict__ Wq,
    const bf16_t* __restrict__ Wk, const bf16_t* __restrict__ Wv,
    bf16_t* __restrict__ qo, bf16_t* __restrict__ ko, bf16_t* __restrict__ vo) {
  __shared__ __align__(16) bf16_t As[128 * 64];
  __shared__ __align__(16) bf16_t Bs[128 * 64];
  const int n0g = blockIdx.x * 128;
  const int m0 = blockIdx.y * 128;
  const bf16_t* B;
  bf16_t* O;
  int Hn, n0;
  if (n0g < 2048)      { B = Wq; O = qo; Hn = 16; n0 = n0g; }
  else if (n0g < 2560) { B = Wk; O = ko; Hn = 4;  n0 = n0g - 2048; }
  else                 { B = Wv; O = vo; Hn = 4;  n0 = n0g - 2560; }
  f32x4 acc[4][4] = {};
  gemm_tile(x, B, 2048, m0, n0, As, Bs, acc);
  const int lane = threadIdx.x & 63, w = threadIdx.x >> 6;
  const int quad = lane >> 4, l16 = lane & 15;
  const int wm = (w >> 1) * 64, wn = (w & 1) * 64;
#pragma unroll
  for (int im = 0; im < 4; ++im)
#pragma unroll
    for (int in_ = 0; in_ < 4; ++in_)
#pragma unroll
      for (int r = 0; r < 4; ++r) {
        int gr = m0 + wm + im * 16 + quad * 4 + r;
        int gc = n0 + wn + in_ * 16 + l16;
        int bb = gr >> 11, ss = gr & 2047, hh = gc >> 7, dd = gc & 127;
        O[(((size_t)bb * Hn + hh) * 2048 + ss) * 128 + dd] = (bf16_t)acc[im][in_][r];
      }
}

// ---------- output projection: out = ctx(bf16) * Wo(bf16)^T, fp32 out --------
__global__ __launch_bounds__(256) void out_gemm(const bf16_t* __restrict__ ctx,
                                                const bf16_t* __restrict__ Wo,
                                                float* __restrict__ out) {
  __shared__ __align__(16) bf16_t As[128 * 64];
  __shared__ __align__(16) bf16_t Bs[128 * 64];
  const int n0 = blockIdx.x * 128, m0 = blockIdx.y * 128;
  f32x4 acc[4][4] = {};
  gemm_tile(ctx, Wo, 2048, m0, n0, As, Bs, acc);
  const int lane = threadIdx.x & 63, w = threadIdx.x >> 6;
  const int quad = lane >> 4, l16 = lane & 15;
  const int wm = (w >> 1) * 64, wn = (w & 1) * 64;
#pragma unroll
  for (int im = 0; im < 4; ++im)
#pragma unroll
    for (int in_ = 0; in_ < 4; ++in_)
#pragma unroll
      for (int r = 0; r < 4; ++r) {
        int gr = m0 + wm + im * 16 + quad * 4 + r;
        int gc = n0 + wn + in_ * 16 + l16;
        out[(size_t)gr * 2048 + gc] = acc[im][in_][r];
      }
}

// ---------- merged RMSNorm + RoPE for q and k (in place), one wave per row ----
__global__ __launch_bounds__(256) void rmsnorm_rope_all(
    bf16_t* __restrict__ qx, bf16_t* __restrict__ kx,
    const float* __restrict__ qw, const float* __restrict__ kw,
    const float* __restrict__ cs, const float* __restrict__ sn, float qscale) {
  int blk = blockIdx.x;
  bf16_t* basep;
  const float* wgt;
  float outscale;
  int row;
  if (blk < 16384) { basep = qx; wgt = qw; outscale = qscale; row = blk * 4 + (threadIdx.x >> 6); }
  else { basep = kx; wgt = kw; outscale = 1.0f; row = (blk - 16384) * 4 + (threadIdx.x >> 6); }
  const int lane = threadIdx.x & 63;
  const int pos = row & 2047;
  bf16_t* p = basep + (size_t)row * 128;
  float v1 = (float)p[lane];
  float v2 = (float)p[lane + 64];
  float ss = v1 * v1 + v2 * v2;
#pragma unroll
  for (int m = 32; m; m >>= 1) ss += __shfl_xor(ss, m);
  float rr = rsqrtf(ss * (1.0f / 128.0f) + 1e-6f);
  float n1 = v1 * rr * wgt[lane];
  float n2 = v2 * rr * wgt[lane + 64];
  float c1 = cs[pos * 128 + lane],      s1 = sn[pos * 128 + lane];
  float c2 = cs[pos * 128 + lane + 64], s2 = sn[pos * 128 + lane + 64];
  p[lane]      = (bf16_t)((n1 * c1 - n2 * s1) * outscale);
  p[lane + 64] = (bf16_t)((n2 * c2 + n1 * s2) * outscale);
}

// ---------- V transpose: [BG,S,HD] -> [BG,HD,S] ----------
__global__ __launch_bounds__(256) void vtrans(const bf16_t* __restrict__ v,
                                              bf16_t* __restrict__ vt) {
  __shared__ bf16_t t[64][72];
  const int bg = blockIdx.z, t0 = blockIdx.x * 64, d0 = blockIdx.y * 64;
  const int tid = threadIdx.x;
  const int r = tid >> 3, c = (tid & 7) * 8;
  const bf16_t* src = v + ((size_t)bg * 2048 + t0) * 128 + d0;
#pragma unroll
  for (int it = 0; it < 2; ++it) {
    uint4 val = *(const uint4*)(src + (size_t)(r + it * 32) * 128 + c);
    *(uint4*)&t[r + it * 32][c] = val;
  }
  __syncthreads();
#pragma unroll
  for (int it = 0; it < 2; ++it) {
    int d = r + it * 32;
    bf16_t tmp[8];
#pragma unroll
    for (int j = 0; j < 8; ++j) tmp[j] = t[c + j][d];
    *(uint4*)(vt + ((size_t)bg * 128 + d0 + d) * 2048 + t0 + c) = *(uint4*)tmp;
  }
}

// ---------- flash attention: GQA, 2 heads/block, transposed QK ----------------
// R10: grid (128,8,2) = 2048 blocks. Block x handles ONE q-tile qt=127-x (long
// blocks dispatch first for load balance), heads {g*4+hb*2, g*4+hb*2+1} where
// g=y>>1, hb=y&1. Per tile: 16 q-rows x 2 heads; K-loop in 64-col tiles.
// S^T = K*Q^T (operand swap) puts a lane's 4 values on 4 consecutive kcols of
// one q-row -> one packed bf16x4 8B P-write per head + scalar lsum per head.
// P: XOR-swizzled ping-pong LDS, one barrier/iter. Fixed-base softmax
// (HD^-0.5*log2e folded into q scale).
__global__ __launch_bounds__(256) void attn_kernel(const bf16_t* __restrict__ q,
    const bf16_t* __restrict__ k, const bf16_t* __restrict__ vt,
    bf16_t* __restrict__ ctx) {
  __shared__ __align__(16) char Plds[2][2][2048];  // [pb][h][16 rows x 128B]
  __shared__ __align__(16) float lred[2][16][4];
  const int qt = 127 - blockIdx.x;          // long q-tiles first
  const int gh = blockIdx.y, b = blockIdx.z;
  const int g = gh >> 1, h0 = (gh & 1) * 2; // head pair within group
  const int tid = threadIdx.x, w = tid >> 6, lane = tid & 63;
  const int quad = lane >> 4, l16 = lane & 15;
  const bf16_t* kp = k + ((size_t)b * 4 + g) * 2048 * 128 +
                     (size_t)(w * 16 + l16) * 128 + quad * 8;
  const bf16_t* vp = vt + ((size_t)b * 4 + g) * 128 * 2048 +
                     (size_t)(w * 32 + l16) * 2048 + quad * 8;

  // Q A-fragments: 16 rows (m=l16) per head (32 VGPR)
  bf16x8 qf[2][4];
#pragma unroll
  for (int h = 0; h < 2; ++h)
#pragma unroll
    for (int kk = 0; kk < 4; ++kk)
      qf[h][kk] = *(const bf16x8*)(q +
          (((size_t)b * 16 + g * 4 + h0 + h) * 2048 + (size_t)qt * 16 + l16) * 128 +
          kk * 32 + quad * 8);

  f32x4 oacc[2][2] = {};
  float lsum[2] = {};
  const int nkt = (qt >> 2) + 1;
  for (int kt = 0; kt < nkt; ++kt) {
    // K fragments (A-operand of S^T: m = kcol w*16+l16), one fetch, 2 heads
    const bf16_t* kro = kp + (size_t)kt * 64 * 128;
    bf16x8 kf[4];
#pragma unroll
    for (int kk = 0; kk < 4; ++kk) kf[kk] = *(const bf16x8*)(kro + kk * 32);
    // V fragments (B-layout n=l16 -> d = w*32+nd*16+l16), used after barrier
    const bf16_t* vro = vp + (size_t)kt * 64;
    bf16x8 vf[2][2];
#pragma unroll
    for (int nd = 0; nd < 2; ++nd)
#pragma unroll
      for (int kkp = 0; kkp < 2; ++kkp)
        vf[nd][kkp] = *(const bf16x8*)(vro + (size_t)nd * 16 * 2048 + kkp * 32);

    // S^T = K Q^T: C row = kcol_local (quad*4+r), col = qrow_local (l16)
    f32x4 sacc[2] = {};
#pragma unroll
    for (int kk = 0; kk < 4; ++kk)
#pragma unroll
      for (int h = 0; h < 2; ++h)
        sacc[h] = __builtin_amdgcn_mfma_f32_16x16x32_bf16(kf[kk], qf[h][kk],
                                                          sacc[h], 0, 0, 0);
    if (kt == nkt - 1) {  // diagonal tile: mask kcol > qrow
      int kcol = kt * 64 + w * 16 + quad * 4;
      int qrow = qt * 16 + l16;
#pragma unroll
      for (int r = 0; r < 4; ++r)
        if (kcol + r > qrow)
#pragma unroll
          for (int h = 0; h < 2; ++h) sacc[h][r] = -1e30f;
    }

    // softmax numerator + packed 8B P-write (row = qrow l16, 4 consec kcols)
    const int pb = kt & 1;
    const int c0 = w * 2 + (quad >> 1);
    const int woff = l16 * 128 + ((c0 ^ (l16 & 7)) << 4) + ((quad & 1) << 3);
#pragma unroll
    for (int h = 0; h < 2; ++h) {
      float p0 = __builtin_amdgcn_exp2f(sacc[h][0]);
      float p1 = __builtin_amdgcn_exp2f(sacc[h][1]);
      float p2 = __builtin_amdgcn_exp2f(sacc[h][2]);
      float p3 = __builtin_amdgcn_exp2f(sacc[h][3]);
      lsum[h] += (p0 + p1) + (p2 + p3);
      bf16x4 pk;
      pk[0] = (bf16_t)p0; pk[1] = (bf16_t)p1; pk[2] = (bf16_t)p2; pk[3] = (bf16_t)p3;
      *(bf16x4*)(Plds[pb][h] + woff) = pk;
    }
    __syncthreads();  // the only barrier in the loop

    // O += P * V: A = P (m=qrow l16, k=kcol quad*8+j), B = V^T
#pragma unroll
    for (int kkp = 0; kkp < 2; ++kkp) {
      bf16x8 pf[2];
#pragma unroll
      for (int h = 0; h < 2; ++h)
        pf[h] = *(const bf16x8*)(Plds[pb][h] + l16 * 128 +
                                 (((kkp * 4 + quad) ^ (l16 & 7)) << 4));
#pragma unroll
      for (int nd = 0; nd < 2; ++nd)
#pragma unroll
        for (int h = 0; h < 2; ++h)
          oacc[h][nd] = __builtin_amdgcn_mfma_f32_16x16x32_bf16(
              pf[h], vf[nd][kkp], oacc[h][nd], 0, 0, 0);
    }
  }

  // row-sum: lane's lsum covers its 4 kcols at qrow=l16; reduce across quads
  // (lanes l16, l16+16, l16+32, l16+48) then across waves via LDS.
#pragma unroll
  for (int h = 0; h < 2; ++h) {
    float v = lsum[h];
    v += __shfl_xor(v, 16);
    v += __shfl_xor(v, 32);
    if (quad == 0) lred[h][l16][w] = v;
  }
  __syncthreads();
  // epilogue: oacc C-layout row = qrow_local quad*4+r, col = d_local l16
#pragma unroll
  for (int h = 0; h < 2; ++h)
#pragma unroll
    for (int r = 0; r < 4; ++r) {
      int row = quad * 4 + r;
      f32x4 t = *(const f32x4*)lred[h][row];
      float inv = 1.f / (t[0] + t[1] + t[2] + t[3]);
      int pos = qt * 16 + row;
      size_t base = (((size_t)b * 2048 + pos) * 16 + g * 4 + h0 + h) * 128;
#pragma unroll
      for (int nd = 0; nd < 2; ++nd)
        ctx[base + w * 32 + nd * 16 + l16] = (bf16_t)(oacc[h][nd][r] * inv);
    }
}

extern "C" void kernel_launch(void* const* d_in, const int* in_sizes, int n_in,
                              void* d_out, int out_size, void* d_ws, size_t ws_size,
                              hipStream_t stream) {
  (void)in_sizes; (void)n_in; (void)out_size; (void)ws_size;
  const float* x    = (const float*)d_in[0];
  const float* cosp = (const float*)d_in[2];
  const float* sinp = (const float*)d_in[3];
  const float* Wq   = (const float*)d_in[4];
  const float* Wk   = (const float*)d_in[5];
  const float* Wv   = (const float*)d_in[6];
  const float* Wo   = (const float*)d_in[7];
  const float* qnw  = (const float*)d_in[8];
  const float* knw  = (const float*)d_in[9];
  float* out = (float*)d_out;

  char* ws = (char*)d_ws;
  bf16_t* qb  = (bf16_t*)(ws);               // 16777216 B
  bf16_t* kb  = (bf16_t*)(ws + 16777216);    //  4194304 B
  bf16_t* vb  = (bf16_t*)(ws + 20971520);    //  4194304 B
  bf16_t* vtb = (bf16_t*)(ws + 25165824);    //  4194304 B
  bf16_t* ctx = (bf16_t*)(ws + 29360128);    // 16777216 B
  bf16_t* xb  = (bf16_t*)(ws + 29360128);    // aliases ctx (dead before attn)
  bf16_t* wqb = (bf16_t*)(ws + 46137344);    //  8388608 B
  bf16_t* wob = (bf16_t*)(ws + 46137344);    // aliases wqb (cast after qkv)
  bf16_t* wkb = (bf16_t*)(ws + 54525952);    //  2097152 B
  bf16_t* wvb = (bf16_t*)(ws + 56623104);    //  2097152 B

  cast_all<<<7168, 256, 0, stream>>>(x, Wq, Wk, Wv, xb, wqb, wkb, wvb);
  qkv_gemm<<<dim3(24, 32), 256, 0, stream>>>(xb, wqb, wkb, wvb, qb, kb, vb);
  // q scale = HD^-0.5 * log2(e) folded for fixed-base exp2 softmax
  rmsnorm_rope_all<<<20480, 256, 0, stream>>>(qb, kb, qnw, knw, cosp, sinp,
                                              0.12751742902f);
  vtrans<<<dim3(32, 2, 8), 256, 0, stream>>>(vb, vtb);
  attn_kernel<<<dim3(128, 8, 2), 256, 0, stream>>>(qb, kb, vtb, ctx);
  cast_f32_bf16<<<2048, 256, 0, stream>>>(Wo, wob);
  out_gemm<<<dim3(16, 32), 256, 0, stream>>>(ctx, wob, out);
}

// Round 2
// 398.978 us; speedup vs baseline: 1.1186x; 1.1186x over previous
//
#include <hip/hip_runtime.h>
#include <hip/hip_bf16.h>

// GroupedQueryAttention: B=2,S=2048,D=2048,H=16,G=4,HD=128, causal, rmsnorm+rope.
// Inputs fp32; OUTPUT fp32. Internal compute bf16 MFMA / fp32 accumulate.
// R11: attn = R9's uniform paired q-tiles {qi,127-qi} (33 iters/block, perfect
// per-CU balance under dispatch aliasing) + R10's 2-head split (grid 64x8x2 =
// 1024 blocks = 4 blocks/CU = 16 waves/CU for latency hiding).
// R10's 1-tile/block variant aliased same-qt blocks onto the same CU -> 2.3x
// regression; pairing makes duration uniform so aliasing is harmless.
// ws (58.7 MB): qb | kb | vb | vtb | ctx(=xb alias) | wqb(=wob) | wkb | wvb

typedef __bf16 bf16_t;
using bf16x4 = __attribute__((ext_vector_type(4))) __bf16;
using bf16x8 = __attribute__((ext_vector_type(8))) __bf16;
using f32x4  = __attribute__((ext_vector_type(4))) float;

#define LDSCP16(gp, lp)                                                       \
  __builtin_amdgcn_global_load_lds(                                           \
      (__attribute__((address_space(1))) void*)(gp),                          \
      (__attribute__((address_space(3))) void*)(lp), 16, 0, 0)

// ---------- merged fp32 -> bf16 casts: x | Wq | Wk | Wv ----------
__global__ __launch_bounds__(256) void cast_all(
    const float* __restrict__ x, const float* __restrict__ wq,
    const float* __restrict__ wk, const float* __restrict__ wv,
    bf16_t* __restrict__ xb, bf16_t* __restrict__ wqb,
    bf16_t* __restrict__ wkb, bf16_t* __restrict__ wvb) {
  int blk = blockIdx.x;
  const float* s;
  bf16_t* d;
  size_t base;
  if (blk < 4096)      { s = x;  d = xb;  base = blk; }
  else if (blk < 6144) { s = wq; d = wqb; base = blk - 4096; }
  else if (blk < 6656) { s = wk; d = wkb; base = blk - 6144; }
  else                 { s = wv; d = wvb; base = blk - 6656; }
  size_t i = base * 256 + threadIdx.x;
  const float* g = s + i * 8;
  f32x4 u0 = *(const f32x4*)g;
  f32x4 u1 = *(const f32x4*)(g + 4);
  bf16x8 v;
  v[0] = (bf16_t)u0[0]; v[1] = (bf16_t)u0[1]; v[2] = (bf16_t)u0[2]; v[3] = (bf16_t)u0[3];
  v[4] = (bf16_t)u1[0]; v[5] = (bf16_t)u1[1]; v[6] = (bf16_t)u1[2]; v[7] = (bf16_t)u1[3];
  *(bf16x8*)(d + i * 8) = v;
}

// ---------- single fp32 -> bf16 cast (Wo, after qkv frees wqb) ----------
__global__ __launch_bounds__(256) void cast_f32_bf16(const float* __restrict__ src,
                                                     bf16_t* __restrict__ dst) {
  size_t i = (size_t)blockIdx.x * 256 + threadIdx.x;
  const float* g = src + i * 8;
  f32x4 u0 = *(const f32x4*)g;
  f32x4 u1 = *(const f32x4*)(g + 4);
  bf16x8 v;
  v[0] = (bf16_t)u0[0]; v[1] = (bf16_t)u0[1]; v[2] = (bf16_t)u0[2]; v[3] = (bf16_t)u0[3];
  v[4] = (bf16_t)u1[0]; v[5] = (bf16_t)u1[1]; v[6] = (bf16_t)u1[2]; v[7] = (bf16_t)u1[3];
  *(bf16x8*)(dst + i * 8) = v;
}

// ---------- 128x128-tile GEMM mainloop: C = A[M,K] * B[N,K]^T (both bf16) ----
// global_load_lds w16, source-side XOR chunk swizzle; frag reads 2-way (free).
__device__ __forceinline__ void gemm_tile(const bf16_t* __restrict__ A,
                                          const bf16_t* __restrict__ B, int K,
                                          int m0, int n0, bf16_t* As, bf16_t* Bs,
                                          f32x4 acc[4][4]) {
  const int tid = threadIdx.x;
  const int lane = tid & 63, w = tid >> 6;
  const int quad = lane >> 4, l16 = lane & 15;
  const int wm = (w >> 1) * 64, wn = (w & 1) * 64;
  char* AsB = (char*)As;
  char* BsB = (char*)Bs;
  const int nkt = K >> 6;
  for (int kt = 0; kt < nkt; ++kt) {
#pragma unroll
    for (int i = 0; i < 4; ++i) {
      int s = i * 256 + tid;
      int row = s >> 3, ch = s & 7;
      int sc = ch ^ (row & 7);
      LDSCP16(A + (size_t)(m0 + row) * K + kt * 64 + sc * 8, As + s * 8);
      LDSCP16(B + (size_t)(n0 + row) * K + kt * 64 + sc * 8, Bs + s * 8);
    }
    __syncthreads();
#pragma unroll
    for (int kk = 0; kk < 2; ++kk) {
      bf16x8 af[4], bfv[4];
#pragma unroll
      for (int i = 0; i < 4; ++i) {
        int ra = wm + i * 16 + l16;
        af[i] = *(const bf16x8*)(AsB + ra * 128 + (((kk * 4 + quad) ^ (ra & 7)) << 4));
        int rb = wn + i * 16 + l16;
        bfv[i] = *(const bf16x8*)(BsB + rb * 128 + (((kk * 4 + quad) ^ (rb & 7)) << 4));
      }
#pragma unroll
      for (int im = 0; im < 4; ++im)
#pragma unroll
        for (int in_ = 0; in_ < 4; ++in_)
          acc[im][in_] = __builtin_amdgcn_mfma_f32_16x16x32_bf16(
              af[im], bfv[in_], acc[im][in_], 0, 0, 0);
    }
    __syncthreads();
  }
}

// ---------- fused QKV projection; writes head-major [B,Hn,S,HD] bf16 ----------
__global__ __launch_bounds__(256) void qkv_gemm(
    const bf16_t* __restrict__ x, const bf16_t* __restrict__ Wq,
    const bf16_t* __restrict__ Wk, const bf16_t* __restrict__ Wv,
    bf16_t* __restrict__ qo, bf16_t* __restrict__ ko, bf16_t* __restrict__ vo) {
  __shared__ __align__(16) bf16_t As[128 * 64];
  __shared__ __align__(16) bf16_t Bs[128 * 64];
  const int n0g = blockIdx.x * 128;
  const int m0 = blockIdx.y * 128;
  const bf16_t* B;
  bf16_t* O;
  int Hn, n0;
  if (n0g < 2048)      { B = Wq; O = qo; Hn = 16; n0 = n0g; }
  else if (n0g < 2560) { B = Wk; O = ko; Hn = 4;  n0 = n0g - 2048; }
  else                 { B = Wv; O = vo; Hn = 4;  n0 = n0g - 2560; }
  f32x4 acc[4][4] = {};
  gemm_tile(x, B, 2048, m0, n0, As, Bs, acc);
  const int lane = threadIdx.x & 63, w = threadIdx.x >> 6;
  const int quad = lane >> 4, l16 = lane & 15;
  const int wm = (w >> 1) * 64, wn = (w & 1) * 64;
#pragma unroll
  for (int im = 0; im < 4; ++im)
#pragma unroll
    for (int in_ = 0; in_ < 4; ++in_)
#pragma unroll
      for (int r = 0; r < 4; ++r) {
        int gr = m0 + wm + im * 16 + quad * 4 + r;
        int gc = n0 + wn + in_ * 16 + l16;
        int bb = gr >> 11, ss = gr & 2047, hh = gc >> 7, dd = gc & 127;
        O[(((size_t)bb * Hn + hh) * 2048 + ss) * 128 + dd] = (bf16_t)acc[im][in_][r];
      }
}

// ---------- output projection: out = ctx(bf16) * Wo(bf16)^T, fp32 out --------
__global__ __launch_bounds__(256) void out_gemm(const bf16_t* __restrict__ ctx,
                                                const bf16_t* __restrict__ Wo,
                                                float* __restrict__ out) {
  __shared__ __align__(16) bf16_t As[128 * 64];
  __shared__ __align__(16) bf16_t Bs[128 * 64];
  const int n0 = blockIdx.x * 128, m0 = blockIdx.y * 128;
  f32x4 acc[4][4] = {};
  gemm_tile(ctx, Wo, 2048, m0, n0, As, Bs, acc);
  const int lane = threadIdx.x & 63, w = threadIdx.x >> 6;
  const int quad = lane >> 4, l16 = lane & 15;
  const int wm = (w >> 1) * 64, wn = (w & 1) * 64;
#pragma unroll
  for (int im = 0; im < 4; ++im)
#pragma unroll
    for (int in_ = 0; in_ < 4; ++in_)
#pragma unroll
      for (int r = 0; r < 4; ++r) {
        int gr = m0 + wm + im * 16 + quad * 4 + r;
        int gc = n0 + wn + in_ * 16 + l16;
        out[(size_t)gr * 2048 + gc] = acc[im][in_][r];
      }
}

// ---------- merged RMSNorm + RoPE for q and k (in place), one wave per row ----
__global__ __launch_bounds__(256) void rmsnorm_rope_all(
    bf16_t* __restrict__ qx, bf16_t* __restrict__ kx,
    const float* __restrict__ qw, const float* __restrict__ kw,
    const float* __restrict__ cs, const float* __restrict__ sn, float qscale) {
  int blk = blockIdx.x;
  bf16_t* basep;
  const float* wgt;
  float outscale;
  int row;
  if (blk < 16384) { basep = qx; wgt = qw; outscale = qscale; row = blk * 4 + (threadIdx.x >> 6); }
  else { basep = kx; wgt = kw; outscale = 1.0f; row = (blk - 16384) * 4 + (threadIdx.x >> 6); }
  const int lane = threadIdx.x & 63;
  const int pos = row & 2047;
  bf16_t* p = basep + (size_t)row * 128;
  float v1 = (float)p[lane];
  float v2 = (float)p[lane + 64];
  float ss = v1 * v1 + v2 * v2;
#pragma unroll
  for (int m = 32; m; m >>= 1) ss += __shfl_xor(ss, m);
  float rr = rsqrtf(ss * (1.0f / 128.0f) + 1e-6f);
  float n1 = v1 * rr * wgt[lane];
  float n2 = v2 * rr * wgt[lane + 64];
  float c1 = cs[pos * 128 + lane],      s1 = sn[pos * 128 + lane];
  float c2 = cs[pos * 128 + lane + 64], s2 = sn[pos * 128 + lane + 64];
  p[lane]      = (bf16_t)((n1 * c1 - n2 * s1) * outscale);
  p[lane + 64] = (bf16_t)((n2 * c2 + n1 * s2) * outscale);
}

// ---------- V transpose: [BG,S,HD] -> [BG,HD,S] ----------
__global__ __launch_bounds__(256) void vtrans(const bf16_t* __restrict__ v,
                                              bf16_t* __restrict__ vt) {
  __shared__ bf16_t t[64][72];
  const int bg = blockIdx.z, t0 = blockIdx.x * 64, d0 = blockIdx.y * 64;
  const int tid = threadIdx.x;
  const int r = tid >> 3, c = (tid & 7) * 8;
  const bf16_t* src = v + ((size_t)bg * 2048 + t0) * 128 + d0;
#pragma unroll
  for (int it = 0; it < 2; ++it) {
    uint4 val = *(const uint4*)(src + (size_t)(r + it * 32) * 128 + c);
    *(uint4*)&t[r + it * 32][c] = val;
  }
  __syncthreads();
#pragma unroll
  for (int it = 0; it < 2; ++it) {
    int d = r + it * 32;
    bf16_t tmp[8];
#pragma unroll
    for (int j = 0; j < 8; ++j) tmp[j] = t[c + j][d];
    *(uint4*)(vt + ((size_t)bg * 128 + d0 + d) * 2048 + t0 + c) = *(uint4*)tmp;
  }
}

// ---------- flash attention: GQA, 2 heads/block, paired q-tiles, transposed QK
// R11: grid (64,8,2) = 1024 blocks, 4/CU. Block (qi,gh,b) does q-tiles
// {qi, 127-qi} -> nkt sums to 33 for EVERY block: uniform duration, so the
// same-x -> same-CU dispatch aliasing cannot unbalance CUs (R10 lesson).
// Heads {g*4+hb*2, +1} where g=gh>>1, hb=gh&1. Per tile: 16 q-rows x 2 heads.
// S^T = K*Q^T (operand swap) puts a lane's 4 values on 4 consecutive kcols of
// one q-row -> one packed bf16x4 8B P-write per head + scalar lsum per head.
// P: XOR-swizzled ping-pong LDS, one barrier/iter. Fixed-base softmax
// (HD^-0.5*log2e folded into q scale).
__global__ __launch_bounds__(256) void attn_kernel(const bf16_t* __restrict__ q,
    const bf16_t* __restrict__ k, const bf16_t* __restrict__ vt,
    bf16_t* __restrict__ ctx) {
  __shared__ __align__(16) char Plds[2][2][2048];  // [pb][h][16 rows x 128B]
  __shared__ __align__(16) float lred[2][16][4];
  const int qi = blockIdx.x;
  const int gh = blockIdx.y, b = blockIdx.z;
  const int g = gh >> 1, h0 = (gh & 1) * 2; // head pair within group
  const int tid = threadIdx.x, w = tid >> 6, lane = tid & 63;
  const int quad = lane >> 4, l16 = lane & 15;
  const bf16_t* kp = k + ((size_t)b * 4 + g) * 2048 * 128 +
                     (size_t)(w * 16 + l16) * 128 + quad * 8;
  const bf16_t* vp = vt + ((size_t)b * 4 + g) * 128 * 2048 +
                     (size_t)(w * 32 + l16) * 2048 + quad * 8;

#pragma unroll 1
  for (int ph = 0; ph < 2; ++ph) {
    const int qt = ph ? 127 - qi : qi;

    // Q A-fragments: 16 rows (m=l16) per head (32 VGPR)
    bf16x8 qf[2][4];
#pragma unroll
    for (int h = 0; h < 2; ++h)
#pragma unroll
      for (int kk = 0; kk < 4; ++kk)
        qf[h][kk] = *(const bf16x8*)(q +
            (((size_t)b * 16 + g * 4 + h0 + h) * 2048 + (size_t)qt * 16 + l16) * 128 +
            kk * 32 + quad * 8);

    f32x4 oacc[2][2] = {};
    float lsum[2] = {};
    const int nkt = (qt >> 2) + 1;
    for (int kt = 0; kt < nkt; ++kt) {
      // K fragments (A-operand of S^T: m = kcol w*16+l16), one fetch, 2 heads
      const bf16_t* kro = kp + (size_t)kt * 64 * 128;
      bf16x8 kf[4];
#pragma unroll
      for (int kk = 0; kk < 4; ++kk) kf[kk] = *(const bf16x8*)(kro + kk * 32);
      // V fragments (B-layout n=l16 -> d = w*32+nd*16+l16), used after barrier
      const bf16_t* vro = vp + (size_t)kt * 64;
      bf16x8 vf[2][2];
#pragma unroll
      for (int nd = 0; nd < 2; ++nd)
#pragma unroll
        for (int kkp = 0; kkp < 2; ++kkp)
          vf[nd][kkp] = *(const bf16x8*)(vro + (size_t)nd * 16 * 2048 + kkp * 32);

      // S^T = K Q^T: C row = kcol_local (quad*4+r), col = qrow_local (l16)
      f32x4 sacc[2] = {};
#pragma unroll
      for (int kk = 0; kk < 4; ++kk)
#pragma unroll
        for (int h = 0; h < 2; ++h)
          sacc[h] = __builtin_amdgcn_mfma_f32_16x16x32_bf16(kf[kk], qf[h][kk],
                                                            sacc[h], 0, 0, 0);
      if (kt == nkt - 1) {  // diagonal tile: mask kcol > qrow
        int kcol = kt * 64 + w * 16 + quad * 4;
        int qrow = qt * 16 + l16;
#pragma unroll
        for (int r = 0; r < 4; ++r)
          if (kcol + r > qrow)
#pragma unroll
            for (int h = 0; h < 2; ++h) sacc[h][r] = -1e30f;
      }

      // softmax numerator + packed 8B P-write (row = qrow l16, 4 consec kcols)
      const int pb = kt & 1;
      const int c0 = w * 2 + (quad >> 1);
      const int woff = l16 * 128 + ((c0 ^ (l16 & 7)) << 4) + ((quad & 1) << 3);
#pragma unroll
      for (int h = 0; h < 2; ++h) {
        float p0 = __builtin_amdgcn_exp2f(sacc[h][0]);
        float p1 = __builtin_amdgcn_exp2f(sacc[h][1]);
        float p2 = __builtin_amdgcn_exp2f(sacc[h][2]);
        float p3 = __builtin_amdgcn_exp2f(sacc[h][3]);
        lsum[h] += (p0 + p1) + (p2 + p3);
        bf16x4 pk;
        pk[0] = (bf16_t)p0; pk[1] = (bf16_t)p1; pk[2] = (bf16_t)p2; pk[3] = (bf16_t)p3;
        *(bf16x4*)(Plds[pb][h] + woff) = pk;
      }
      __syncthreads();  // the only barrier in the loop

      // O += P * V: A = P (m=qrow l16, k=kcol quad*8+j), B = V^T
#pragma unroll
      for (int kkp = 0; kkp < 2; ++kkp) {
        bf16x8 pf[2];
#pragma unroll
        for (int h = 0; h < 2; ++h)
          pf[h] = *(const bf16x8*)(Plds[pb][h] + l16 * 128 +
                                   (((kkp * 4 + quad) ^ (l16 & 7)) << 4));
#pragma unroll
        for (int nd = 0; nd < 2; ++nd)
#pragma unroll
          for (int h = 0; h < 2; ++h)
            oacc[h][nd] = __builtin_amdgcn_mfma_f32_16x16x32_bf16(
                pf[h], vf[nd][kkp], oacc[h][nd], 0, 0, 0);
      }
    }

    // row-sum: lane's lsum covers its 4 kcols at qrow=l16; reduce across quads
    // (lanes l16, l16+16, l16+32, l16+48) then across waves via LDS.
#pragma unroll
    for (int h = 0; h < 2; ++h) {
      float v = lsum[h];
      v += __shfl_xor(v, 16);
      v += __shfl_xor(v, 32);
      if (quad == 0) lred[h][l16][w] = v;
    }
    __syncthreads();
    // epilogue: oacc C-layout row = qrow_local quad*4+r, col = d_local l16
#pragma unroll
    for (int h = 0; h < 2; ++h)
#pragma unroll
      for (int r = 0; r < 4; ++r) {
        int row = quad * 4 + r;
        f32x4 t = *(const f32x4*)lred[h][row];
        float inv = 1.f / (t[0] + t[1] + t[2] + t[3]);
        int pos = qt * 16 + row;
        size_t base = (((size_t)b * 2048 + pos) * 16 + g * 4 + h0 + h) * 128;
#pragma unroll
        for (int nd = 0; nd < 2; ++nd)
          ctx[base + w * 32 + nd * 16 + l16] = (bf16_t)(oacc[h][nd][r] * inv);
      }
  }
}

extern "C" void kernel_launch(void* const* d_in, const int* in_sizes, int n_in,
                              void* d_out, int out_size, void* d_ws, size_t ws_size,
                              hipStream_t stream) {
  (void)in_sizes; (void)n_in; (void)out_size; (void)ws_size;
  const float* x    = (const float*)d_in[0];
  const float* cosp = (const float*)d_in[2];
  const float* sinp = (const float*)d_in[3];
  const float* Wq   = (const float*)d_in[4];
  const float* Wk   = (const float*)d_in[5];
  const float* Wv   = (const float*)d_in[6];
  const float* Wo   = (const float*)d_in[7];
  const float* qnw  = (const float*)d_in[8];
  const float* knw  = (const float*)d_in[9];
  float* out = (float*)d_out;

  char* ws = (char*)d_ws;
  bf16_t* qb  = (bf16_t*)(ws);               // 16777216 B
  bf16_t* kb  = (bf16_t*)(ws + 16777216);    //  4194304 B
  bf16_t* vb  = (bf16_t*)(ws + 20971520);    //  4194304 B
  bf16_t* vtb = (bf16_t*)(ws + 25165824);    //  4194304 B
  bf16_t* ctx = (bf16_t*)(ws + 29360128);    // 16777216 B
  bf16_t* xb  = (bf16_t*)(ws + 29360128);    // aliases ctx (dead before attn)
  bf16_t* wqb = (bf16_t*)(ws + 46137344);    //  8388608 B
  bf16_t* wob = (bf16_t*)(ws + 46137344);    // aliases wqb (cast after qkv)
  bf16_t* wkb = (bf16_t*)(ws + 54525952);    //  2097152 B
  bf16_t* wvb = (bf16_t*)(ws + 56623104);    //  2097152 B

  cast_all<<<7168, 256, 0, stream>>>(x, Wq, Wk, Wv, xb, wqb, wkb, wvb);
  qkv_gemm<<<dim3(24, 32), 256, 0, stream>>>(xb, wqb, wkb, wvb, qb, kb, vb);
  // q scale = HD^-0.5 * log2(e) folded for fixed-base exp2 softmax
  rmsnorm_rope_all<<<20480, 256, 0, stream>>>(qb, kb, qnw, knw, cosp, sinp,
                                              0.12751742902f);
  vtrans<<<dim3(32, 2, 8), 256, 0, stream>>>(vb, vtb);
  attn_kernel<<<dim3(64, 8, 2), 256, 0, stream>>>(qb, kb, vtb, ctx);
  cast_f32_bf16<<<2048, 256, 0, stream>>>(Wo, wob);
  out_gemm<<<dim3(16, 32), 256, 0, stream>>>(ctx, wob, out);
}

// Round 3
// 368.014 us; speedup vs baseline: 1.2127x; 1.0841x over previous
//
#include <hip/hip_runtime.h>
#include <hip/hip_bf16.h>

// GroupedQueryAttention: B=2,S=2048,D=2048,H=16,G=4,HD=128, causal, rmsnorm+rope.
// Inputs fp32; OUTPUT fp32. Internal compute bf16 MFMA / fp32 accumulate.
// R12: attn reverted to R9 structure (4 heads/block, paired q-tiles {qi,127-qi},
// grid 64x4x2 — R10/R11 head-splits doubled per-CU K/V traffic+iterations and
// doubled time) + K/V PREFETCH: next tile's loads issue right after the barrier,
// hiding L2 latency under the PV MFMA cluster (T14 issue-early). GEMMs get a
// bijective XCD swizzle (contiguous m-band per XCD -> A-panel L2 reuse).
// ws (58.7 MB): qb | kb | vb | vtb | ctx(=xb alias) | wqb(=wob) | wkb | wvb

typedef __bf16 bf16_t;
using bf16x4 = __attribute__((ext_vector_type(4))) __bf16;
using bf16x8 = __attribute__((ext_vector_type(8))) __bf16;
using f32x4  = __attribute__((ext_vector_type(4))) float;

#define LDSCP16(gp, lp)                                                       \
  __builtin_amdgcn_global_load_lds(                                           \
      (__attribute__((address_space(1))) void*)(gp),                          \
      (__attribute__((address_space(3))) void*)(lp), 16, 0, 0)

// ---------- merged fp32 -> bf16 casts: x | Wq | Wk | Wv ----------
__global__ __launch_bounds__(256) void cast_all(
    const float* __restrict__ x, const float* __restrict__ wq,
    const float* __restrict__ wk, const float* __restrict__ wv,
    bf16_t* __restrict__ xb, bf16_t* __restrict__ wqb,
    bf16_t* __restrict__ wkb, bf16_t* __restrict__ wvb) {
  int blk = blockIdx.x;
  const float* s;
  bf16_t* d;
  size_t base;
  if (blk < 4096)      { s = x;  d = xb;  base = blk; }
  else if (blk < 6144) { s = wq; d = wqb; base = blk - 4096; }
  else if (blk < 6656) { s = wk; d = wkb; base = blk - 6144; }
  else                 { s = wv; d = wvb; base = blk - 6656; }
  size_t i = base * 256 + threadIdx.x;
  const float* g = s + i * 8;
  f32x4 u0 = *(const f32x4*)g;
  f32x4 u1 = *(const f32x4*)(g + 4);
  bf16x8 v;
  v[0] = (bf16_t)u0[0]; v[1] = (bf16_t)u0[1]; v[2] = (bf16_t)u0[2]; v[3] = (bf16_t)u0[3];
  v[4] = (bf16_t)u1[0]; v[5] = (bf16_t)u1[1]; v[6] = (bf16_t)u1[2]; v[7] = (bf16_t)u1[3];
  *(bf16x8*)(d + i * 8) = v;
}

// ---------- single fp32 -> bf16 cast (Wo, after qkv frees wqb) ----------
__global__ __launch_bounds__(256) void cast_f32_bf16(const float* __restrict__ src,
                                                     bf16_t* __restrict__ dst) {
  size_t i = (size_t)blockIdx.x * 256 + threadIdx.x;
  const float* g = src + i * 8;
  f32x4 u0 = *(const f32x4*)g;
  f32x4 u1 = *(const f32x4*)(g + 4);
  bf16x8 v;
  v[0] = (bf16_t)u0[0]; v[1] = (bf16_t)u0[1]; v[2] = (bf16_t)u0[2]; v[3] = (bf16_t)u0[3];
  v[4] = (bf16_t)u1[0]; v[5] = (bf16_t)u1[1]; v[6] = (bf16_t)u1[2]; v[7] = (bf16_t)u1[3];
  *(bf16x8*)(dst + i * 8) = v;
}

// ---------- 128x128-tile GEMM mainloop: C = A[M,K] * B[N,K]^T (both bf16) ----
// global_load_lds w16, source-side XOR chunk swizzle; frag reads 2-way (free).
__device__ __forceinline__ void gemm_tile(const bf16_t* __restrict__ A,
                                          const bf16_t* __restrict__ B, int K,
                                          int m0, int n0, bf16_t* As, bf16_t* Bs,
                                          f32x4 acc[4][4]) {
  const int tid = threadIdx.x;
  const int lane = tid & 63, w = tid >> 6;
  const int quad = lane >> 4, l16 = lane & 15;
  const int wm = (w >> 1) * 64, wn = (w & 1) * 64;
  char* AsB = (char*)As;
  char* BsB = (char*)Bs;
  const int nkt = K >> 6;
  for (int kt = 0; kt < nkt; ++kt) {
#pragma unroll
    for (int i = 0; i < 4; ++i) {
      int s = i * 256 + tid;
      int row = s >> 3, ch = s & 7;
      int sc = ch ^ (row & 7);
      LDSCP16(A + (size_t)(m0 + row) * K + kt * 64 + sc * 8, As + s * 8);
      LDSCP16(B + (size_t)(n0 + row) * K + kt * 64 + sc * 8, Bs + s * 8);
    }
    __syncthreads();
#pragma unroll
    for (int kk = 0; kk < 2; ++kk) {
      bf16x8 af[4], bfv[4];
#pragma unroll
      for (int i = 0; i < 4; ++i) {
        int ra = wm + i * 16 + l16;
        af[i] = *(const bf16x8*)(AsB + ra * 128 + (((kk * 4 + quad) ^ (ra & 7)) << 4));
        int rb = wn + i * 16 + l16;
        bfv[i] = *(const bf16x8*)(BsB + rb * 128 + (((kk * 4 + quad) ^ (rb & 7)) << 4));
      }
#pragma unroll
      for (int im = 0; im < 4; ++im)
#pragma unroll
        for (int in_ = 0; in_ < 4; ++in_)
          acc[im][in_] = __builtin_amdgcn_mfma_f32_16x16x32_bf16(
              af[im], bfv[in_], acc[im][in_], 0, 0, 0);
    }
    __syncthreads();
  }
}

// ---------- fused QKV projection; writes head-major [B,Hn,S,HD] bf16 ----------
// XCD swizzle: 768 wgs, 96/XCD -> each XCD owns a contiguous 4-m-row band.
__global__ __launch_bounds__(256) void qkv_gemm(
    const bf16_t* __restrict__ x, const bf16_t* __restrict__ Wq,
    const bf16_t* __restrict__ Wk, const bf16_t* __restrict__ Wv,
    bf16_t* __restrict__ qo, bf16_t* __restrict__ ko, bf16_t* __restrict__ vo) {
  __shared__ __align__(16) bf16_t As[128 * 64];
  __shared__ __align__(16) bf16_t Bs[128 * 64];
  const int lin = blockIdx.x + blockIdx.y * 24;
  const int swz = (lin & 7) * 96 + (lin >> 3);
  const int n0g = (swz % 24) * 128;
  const int m0 = (swz / 24) * 128;
  const bf16_t* B;
  bf16_t* O;
  int Hn, n0;
  if (n0g < 2048)      { B = Wq; O = qo; Hn = 16; n0 = n0g; }
  else if (n0g < 2560) { B = Wk; O = ko; Hn = 4;  n0 = n0g - 2048; }
  else                 { B = Wv; O = vo; Hn = 4;  n0 = n0g - 2560; }
  f32x4 acc[4][4] = {};
  gemm_tile(x, B, 2048, m0, n0, As, Bs, acc);
  const int lane = threadIdx.x & 63, w = threadIdx.x >> 6;
  const int quad = lane >> 4, l16 = lane & 15;
  const int wm = (w >> 1) * 64, wn = (w & 1) * 64;
#pragma unroll
  for (int im = 0; im < 4; ++im)
#pragma unroll
    for (int in_ = 0; in_ < 4; ++in_)
#pragma unroll
      for (int r = 0; r < 4; ++r) {
        int gr = m0 + wm + im * 16 + quad * 4 + r;
        int gc = n0 + wn + in_ * 16 + l16;
        int bb = gr >> 11, ss = gr & 2047, hh = gc >> 7, dd = gc & 127;
        O[(((size_t)bb * Hn + hh) * 2048 + ss) * 128 + dd] = (bf16_t)acc[im][in_][r];
      }
}

// ---------- output projection: out = ctx(bf16) * Wo(bf16)^T, fp32 out --------
// XCD swizzle: 512 wgs, 64/XCD -> contiguous 4-m-row band per XCD.
__global__ __launch_bounds__(256) void out_gemm(const bf16_t* __restrict__ ctx,
                                                const bf16_t* __restrict__ Wo,
                                                float* __restrict__ out) {
  __shared__ __align__(16) bf16_t As[128 * 64];
  __shared__ __align__(16) bf16_t Bs[128 * 64];
  const int lin = blockIdx.x + blockIdx.y * 16;
  const int swz = (lin & 7) * 64 + (lin >> 3);
  const int n0 = (swz & 15) * 128, m0 = (swz >> 4) * 128;
  f32x4 acc[4][4] = {};
  gemm_tile(ctx, Wo, 2048, m0, n0, As, Bs, acc);
  const int lane = threadIdx.x & 63, w = threadIdx.x >> 6;
  const int quad = lane >> 4, l16 = lane & 15;
  const int wm = (w >> 1) * 64, wn = (w & 1) * 64;
#pragma unroll
  for (int im = 0; im < 4; ++im)
#pragma unroll
    for (int in_ = 0; in_ < 4; ++in_)
#pragma unroll
      for (int r = 0; r < 4; ++r) {
        int gr = m0 + wm + im * 16 + quad * 4 + r;
        int gc = n0 + wn + in_ * 16 + l16;
        out[(size_t)gr * 2048 + gc] = acc[im][in_][r];
      }
}

// ---------- merged RMSNorm + RoPE for q and k (in place), one wave per row ----
__global__ __launch_bounds__(256) void rmsnorm_rope_all(
    bf16_t* __restrict__ qx, bf16_t* __restrict__ kx,
    const float* __restrict__ qw, const float* __restrict__ kw,
    const float* __restrict__ cs, const float* __restrict__ sn, float qscale) {
  int blk = blockIdx.x;
  bf16_t* basep;
  const float* wgt;
  float outscale;
  int row;
  if (blk < 16384) { basep = qx; wgt = qw; outscale = qscale; row = blk * 4 + (threadIdx.x >> 6); }
  else { basep = kx; wgt = kw; outscale = 1.0f; row = (blk - 16384) * 4 + (threadIdx.x >> 6); }
  const int lane = threadIdx.x & 63;
  const int pos = row & 2047;
  bf16_t* p = basep + (size_t)row * 128;
  float v1 = (float)p[lane];
  float v2 = (float)p[lane + 64];
  float ss = v1 * v1 + v2 * v2;
#pragma unroll
  for (int m = 32; m; m >>= 1) ss += __shfl_xor(ss, m);
  float rr = rsqrtf(ss * (1.0f / 128.0f) + 1e-6f);
  float n1 = v1 * rr * wgt[lane];
  float n2 = v2 * rr * wgt[lane + 64];
  float c1 = cs[pos * 128 + lane],      s1 = sn[pos * 128 + lane];
  float c2 = cs[pos * 128 + lane + 64], s2 = sn[pos * 128 + lane + 64];
  p[lane]      = (bf16_t)((n1 * c1 - n2 * s1) * outscale);
  p[lane + 64] = (bf16_t)((n2 * c2 + n1 * s2) * outscale);
}

// ---------- V transpose: [BG,S,HD] -> [BG,HD,S] ----------
__global__ __launch_bounds__(256) void vtrans(const bf16_t* __restrict__ v,
                                              bf16_t* __restrict__ vt) {
  __shared__ bf16_t t[64][72];
  const int bg = blockIdx.z, t0 = blockIdx.x * 64, d0 = blockIdx.y * 64;
  const int tid = threadIdx.x;
  const int r = tid >> 3, c = (tid & 7) * 8;
  const bf16_t* src = v + ((size_t)bg * 2048 + t0) * 128 + d0;
#pragma unroll
  for (int it = 0; it < 2; ++it) {
    uint4 val = *(const uint4*)(src + (size_t)(r + it * 32) * 128 + c);
    *(uint4*)&t[r + it * 32][c] = val;
  }
  __syncthreads();
#pragma unroll
  for (int it = 0; it < 2; ++it) {
    int d = r + it * 32;
    bf16_t tmp[8];
#pragma unroll
    for (int j = 0; j < 8; ++j) tmp[j] = t[c + j][d];
    *(uint4*)(vt + ((size_t)bg * 128 + d0 + d) * 2048 + t0 + c) = *(uint4*)tmp;
  }
}

// ---------- flash attention: GQA head-merged, uniform blocks, transposed QK --
// R12 = R9 structure + K/V prefetch. Block (qi,g,b) does q-tiles {qi,127-qi}
// (33 iters total, uniform). Per tile: 16 q-rows x 4 heads; K-loop in 64-col
// tiles. S^T = K*Q^T (operand swap) -> packed bf16x4 8B P-writes + scalar lsum.
// P: XOR-swizzled ping-pong LDS, one barrier/iter. Prefetch: tile kt+1's K/V
// loads issue right AFTER the barrier (never cross one, so the barrier's
// vmcnt(0) drain ignores them) and their latency hides under the PV MFMAs.
// Fixed-base softmax (HD^-0.5*log2e folded into q scale).
__global__ __launch_bounds__(256) void attn_kernel(const bf16_t* __restrict__ q,
    const bf16_t* __restrict__ k, const bf16_t* __restrict__ vt,
    bf16_t* __restrict__ ctx) {
  __shared__ __align__(16) char Plds[2][4][2048];  // [pb][h][16 rows x 128B]
  __shared__ __align__(16) float lred[4][16][4];
  const int qi = blockIdx.x, g = blockIdx.y, b = blockIdx.z;
  const int tid = threadIdx.x, w = tid >> 6, lane = tid & 63;
  const int quad = lane >> 4, l16 = lane & 15;
  const bf16_t* kp = k + ((size_t)b * 4 + g) * 2048 * 128 +
                     (size_t)(w * 16 + l16) * 128 + quad * 8;
  const bf16_t* vp = vt + ((size_t)b * 4 + g) * 128 * 2048 +
                     (size_t)(w * 32 + l16) * 2048 + quad * 8;

#pragma unroll 1
  for (int ph = 0; ph < 2; ++ph) {
    const int qt = ph ? 127 - qi : qi;

    // Q A-fragments: 16 rows (m=l16) per head (64 VGPR)
    bf16x8 qf[4][4];
#pragma unroll
    for (int h = 0; h < 4; ++h)
#pragma unroll
      for (int kk = 0; kk < 4; ++kk)
        qf[h][kk] = *(const bf16x8*)(q +
            (((size_t)b * 16 + g * 4 + h) * 2048 + (size_t)qt * 16 + l16) * 128 +
            kk * 32 + quad * 8);

    f32x4 oacc[4][2] = {};
    float lsum[4] = {};
    const int nkt = (qt >> 2) + 1;

    // double-buffered K/V fragments (a/b named sets: all indices compile-time)
    bf16x8 kfa[4], vfa[2][2], kfb[4], vfb[2][2];

    auto loadkv = [&](bf16x8 (&KF)[4], bf16x8 (&VF)[2][2], int KT) {
      const bf16_t* kro = kp + (size_t)KT * 64 * 128;
#pragma unroll
      for (int kk = 0; kk < 4; ++kk) KF[kk] = *(const bf16x8*)(kro + kk * 32);
      const bf16_t* vro = vp + (size_t)KT * 64;
#pragma unroll
      for (int nd = 0; nd < 2; ++nd)
#pragma unroll
        for (int kkp = 0; kkp < 2; ++kkp)
          VF[nd][kkp] = *(const bf16x8*)(vro + (size_t)nd * 16 * 2048 + kkp * 32);
    };

    auto process = [&](bf16x8 (&KF)[4], bf16x8 (&VF)[2][2],
                       bf16x8 (&KFN)[4], bf16x8 (&VFN)[2][2], int KT) {
      // S^T = K Q^T: C row = kcol_local (quad*4+r), col = qrow_local (l16)
      f32x4 sacc[4] = {};
#pragma unroll
      for (int kk = 0; kk < 4; ++kk)
#pragma unroll
        for (int h = 0; h < 4; ++h)
          sacc[h] = __builtin_amdgcn_mfma_f32_16x16x32_bf16(KF[kk], qf[h][kk],
                                                            sacc[h], 0, 0, 0);
      if (KT == nkt - 1) {  // diagonal tile: mask kcol > qrow
        int kcol = KT * 64 + w * 16 + quad * 4;
        int qrow = qt * 16 + l16;
#pragma unroll
        for (int r = 0; r < 4; ++r)
          if (kcol + r > qrow)
#pragma unroll
            for (int h = 0; h < 4; ++h) sacc[h][r] = -1e30f;
      }

      // softmax numerator + packed 8B P-write (row = qrow l16, 4 consec kcols)
      const int pb = KT & 1;
      const int c0 = w * 2 + (quad >> 1);
      const int woff = l16 * 128 + ((c0 ^ (l16 & 7)) << 4) + ((quad & 1) << 3);
#pragma unroll
      for (int h = 0; h < 4; ++h) {
        float p0 = __builtin_amdgcn_exp2f(sacc[h][0]);
        float p1 = __builtin_amdgcn_exp2f(sacc[h][1]);
        float p2 = __builtin_amdgcn_exp2f(sacc[h][2]);
        float p3 = __builtin_amdgcn_exp2f(sacc[h][3]);
        lsum[h] += (p0 + p1) + (p2 + p3);
        bf16x4 pk;
        pk[0] = (bf16_t)p0; pk[1] = (bf16_t)p1; pk[2] = (bf16_t)p2; pk[3] = (bf16_t)p3;
        *(bf16x4*)(Plds[pb][h] + woff) = pk;
      }
      __syncthreads();  // the only barrier in the loop

      // prefetch next tile's K/V NOW: latency hides under the PV cluster
      int ktn = (KT + 1 < nkt) ? KT + 1 : KT;
      loadkv(KFN, VFN, ktn);

      // O += P * V: A = P (m=qrow l16, k=kcol quad*8+j), B = V^T
#pragma unroll
      for (int kkp = 0; kkp < 2; ++kkp) {
        bf16x8 pf[4];
#pragma unroll
        for (int h = 0; h < 4; ++h)
          pf[h] = *(const bf16x8*)(Plds[pb][h] + l16 * 128 +
                                   (((kkp * 4 + quad) ^ (l16 & 7)) << 4));
#pragma unroll
        for (int nd = 0; nd < 2; ++nd)
#pragma unroll
          for (int h = 0; h < 4; ++h)
            oacc[h][nd] = __builtin_amdgcn_mfma_f32_16x16x32_bf16(
                pf[h], VF[nd][kkp], oacc[h][nd], 0, 0, 0);
      }
    };

    loadkv(kfa, vfa, 0);
    int kt = 0;
    while (true) {
      process(kfa, vfa, kfb, vfb, kt);
      if (++kt == nkt) break;
      process(kfb, vfb, kfa, vfa, kt);
      if (++kt == nkt) break;
    }

    // row-sum: lane's lsum covers its 4 kcols at qrow=l16; reduce across quads
    // (lanes l16, l16+16, l16+32, l16+48) then across waves via LDS.
#pragma unroll
    for (int h = 0; h < 4; ++h) {
      float v = lsum[h];
      v += __shfl_xor(v, 16);
      v += __shfl_xor(v, 32);
      if (quad == 0) lred[h][l16][w] = v;
    }
    __syncthreads();
    // epilogue: oacc C-layout row = qrow_local quad*4+r, col = d_local l16
#pragma unroll
    for (int h = 0; h < 4; ++h)
#pragma unroll
      for (int r = 0; r < 4; ++r) {
        int row = quad * 4 + r;
        f32x4 t = *(const f32x4*)lred[h][row];
        float inv = 1.f / (t[0] + t[1] + t[2] + t[3]);
        int pos = qt * 16 + row;
        size_t base = (((size_t)b * 2048 + pos) * 16 + g * 4 + h) * 128;
#pragma unroll
        for (int nd = 0; nd < 2; ++nd)
          ctx[base + w * 32 + nd * 16 + l16] = (bf16_t)(oacc[h][nd][r] * inv);
      }
  }
}

extern "C" void kernel_launch(void* const* d_in, const int* in_sizes, int n_in,
                              void* d_out, int out_size, void* d_ws, size_t ws_size,
                              hipStream_t stream) {
  (void)in_sizes; (void)n_in; (void)out_size; (void)ws_size;
  const float* x    = (const float*)d_in[0];
  const float* cosp = (const float*)d_in[2];
  const float* sinp = (const float*)d_in[3];
  const float* Wq   = (const float*)d_in[4];
  const float* Wk   = (const float*)d_in[5];
  const float* Wv   = (const float*)d_in[6];
  const float* Wo   = (const float*)d_in[7];
  const float* qnw  = (const float*)d_in[8];
  const float* knw  = (const float*)d_in[9];
  float* out = (float*)d_out;

  char* ws = (char*)d_ws;
  bf16_t* qb  = (bf16_t*)(ws);               // 16777216 B
  bf16_t* kb  = (bf16_t*)(ws + 16777216);    //  4194304 B
  bf16_t* vb  = (bf16_t*)(ws + 20971520);    //  4194304 B
  bf16_t* vtb = (bf16_t*)(ws + 25165824);    //  4194304 B
  bf16_t* ctx = (bf16_t*)(ws + 29360128);    // 16777216 B
  bf16_t* xb  = (bf16_t*)(ws + 29360128);    // aliases ctx (dead before attn)
  bf16_t* wqb = (bf16_t*)(ws + 46137344);    //  8388608 B
  bf16_t* wob = (bf16_t*)(ws + 46137344);    // aliases wqb (cast after qkv)
  bf16_t* wkb = (bf16_t*)(ws + 54525952);    //  2097152 B
  bf16_t* wvb = (bf16_t*)(ws + 56623104);    //  2097152 B

  cast_all<<<7168, 256, 0, stream>>>(x, Wq, Wk, Wv, xb, wqb, wkb, wvb);
  qkv_gemm<<<dim3(24, 32), 256, 0, stream>>>(xb, wqb, wkb, wvb, qb, kb, vb);
  // q scale = HD^-0.5 * log2(e) folded for fixed-base exp2 softmax
  rmsnorm_rope_all<<<20480, 256, 0, stream>>>(qb, kb, qnw, knw, cosp, sinp,
                                              0.12751742902f);
  vtrans<<<dim3(32, 2, 8), 256, 0, stream>>>(vb, vtb);
  attn_kernel<<<dim3(64, 4, 2), 256, 0, stream>>>(qb, kb, vtb, ctx);
  cast_f32_bf16<<<2048, 256, 0, stream>>>(Wo, wob);
  out_gemm<<<dim3(16, 32), 256, 0, stream>>>(ctx, wob, out);
}

// Round 4
// 361.077 us; speedup vs baseline: 1.2360x; 1.0192x over previous
//
#include <hip/hip_runtime.h>
#include <hip/hip_bf16.h>

// GroupedQueryAttention: B=2,S=2048,D=2048,H=16,G=4,HD=128, causal, rmsnorm+rope.
// Inputs fp32; OUTPUT fp32. Internal compute bf16 MFMA / fp32 accumulate.
// R13: attn reverted to exact R9 (83us known-good; R10-R12 attn variants all
// regressed). GEMMs rewritten to 256x256/BK=64 8-wave phase-split schedule
// (plain-HIP port of the 8-phase template): raw s_barrier (NO vmcnt drain),
// one vmcnt(0)+barrier per K-tile at buffer swap, staging front-loaded in
// phases 0-1 (~3 phases of latency cover), setprio around MFMA clusters,
// source-side XOR chunk swizzle (proven in this kernel already).
// ws (58.7 MB): qb | kb | vb | vtb | ctx(=xb alias) | wqb(=wob) | wkb | wvb

typedef __bf16 bf16_t;
using bf16x4 = __attribute__((ext_vector_type(4))) __bf16;
using bf16x8 = __attribute__((ext_vector_type(8))) __bf16;
using f32x4  = __attribute__((ext_vector_type(4))) float;

#define LDSCP16(gp, lp)                                                       \
  __builtin_amdgcn_global_load_lds(                                           \
      (__attribute__((address_space(1))) void*)(gp),                          \
      (__attribute__((address_space(3))) void*)(lp), 16, 0, 0)

// ---------- merged fp32 -> bf16 casts: x | Wq | Wk | Wv ----------
__global__ __launch_bounds__(256) void cast_all(
    const float* __restrict__ x, const float* __restrict__ wq,
    const float* __restrict__ wk, const float* __restrict__ wv,
    bf16_t* __restrict__ xb, bf16_t* __restrict__ wqb,
    bf16_t* __restrict__ wkb, bf16_t* __restrict__ wvb) {
  int blk = blockIdx.x;
  const float* s;
  bf16_t* d;
  size_t base;
  if (blk < 4096)      { s = x;  d = xb;  base = blk; }
  else if (blk < 6144) { s = wq; d = wqb; base = blk - 4096; }
  else if (blk < 6656) { s = wk; d = wkb; base = blk - 6144; }
  else                 { s = wv; d = wvb; base = blk - 6656; }
  size_t i = base * 256 + threadIdx.x;
  const float* g = s + i * 8;
  f32x4 u0 = *(const f32x4*)g;
  f32x4 u1 = *(const f32x4*)(g + 4);
  bf16x8 v;
  v[0] = (bf16_t)u0[0]; v[1] = (bf16_t)u0[1]; v[2] = (bf16_t)u0[2]; v[3] = (bf16_t)u0[3];
  v[4] = (bf16_t)u1[0]; v[5] = (bf16_t)u1[1]; v[6] = (bf16_t)u1[2]; v[7] = (bf16_t)u1[3];
  *(bf16x8*)(d + i * 8) = v;
}

// ---------- single fp32 -> bf16 cast (Wo, after qkv frees wqb) ----------
__global__ __launch_bounds__(256) void cast_f32_bf16(const float* __restrict__ src,
                                                     bf16_t* __restrict__ dst) {
  size_t i = (size_t)blockIdx.x * 256 + threadIdx.x;
  const float* g = src + i * 8;
  f32x4 u0 = *(const f32x4*)g;
  f32x4 u1 = *(const f32x4*)(g + 4);
  bf16x8 v;
  v[0] = (bf16_t)u0[0]; v[1] = (bf16_t)u0[1]; v[2] = (bf16_t)u0[2]; v[3] = (bf16_t)u0[3];
  v[4] = (bf16_t)u1[0]; v[5] = (bf16_t)u1[1]; v[6] = (bf16_t)u1[2]; v[7] = (bf16_t)u1[3];
  *(bf16x8*)(dst + i * 8) = v;
}

// ---------- 256x256-tile phase-split GEMM mainloop: C = A[M,K]*B[N,K]^T -----
// 512 thr = 8 waves (2M x 4N), wave tile 128x64, BK=64, dbuf LDS 128KB.
// Per K-tile, 4 phases: {ds_read subtile | stage 2 units -> raw s_barrier ->
// setprio(1) 16xMFMA setprio(0) -> raw s_barrier}. Staging of tile g+1 goes
// into the non-read buffer, front-loaded in phases 0-1; one vmcnt(0)+barrier
// at the swap. Raw barriers do NOT drain vmcnt (unlike __syncthreads) -> the
// staging loads stay in flight across phase barriers.
__device__ __forceinline__ void gemm256_loop(const bf16_t* __restrict__ A,
                                             const bf16_t* __restrict__ B,
                                             int K, int m0, int n0,
                                             bf16_t (*As)[256 * 64],
                                             bf16_t (*Bs)[256 * 64],
                                             f32x4 (&acc)[8][4]) {
  const int tid = threadIdx.x;
  const int lane = tid & 63, wid = tid >> 6;
  const int quad = lane >> 4, l16 = lane & 15;
  const int am = (wid >> 2) * 128;   // wave's A-row base (2 M-halves)
  const int bn = (wid & 3) * 64;     // wave's B-row base (4 N-quarters)
  const int NT = K >> 6;

  // stage units [u0,u1) of K-tile g into buffer wb. unit = 512thr x 16B for
  // A and B each (64 tile-rows). Source-side XOR chunk swizzle (dest linear).
  auto stage = [&](int g, int wb, int u0, int u1) {
#pragma unroll
    for (int u = u0; u < u1; ++u) {
      int s = u * 512 + tid;
      int row = s >> 3, sc = (s & 7) ^ (row & 7);
      LDSCP16(A + (size_t)(m0 + row) * K + g * 64 + sc * 8,
              (bf16_t*)As[wb] + s * 8);
      LDSCP16(B + (size_t)(n0 + row) * K + g * 64 + sc * 8,
              (bf16_t*)Bs[wb] + s * 8);
    }
  };

  // prologue: tile 0 -> buf0
  stage(0, 0, 0, 4);
  asm volatile("s_waitcnt vmcnt(0)" ::: "memory");
  __builtin_amdgcn_s_barrier();

  bf16x8 af[4][2], bfr[4][2];

  auto group = [&](int g, int rb) {
    const int wb = rb ^ 1;
    const char* Ab = (const char*)As[rb];
    const char* Bb = (const char*)Bs[rb];
    const bool pf = (g + 1 < NT);

    // ---- P0: ds_read A(mf0-3)x2kk + B(nf0-1)x2kk (12 reads); stage u0-1 ----
#pragma unroll
    for (int mf = 0; mf < 4; ++mf)
#pragma unroll
      for (int kk = 0; kk < 2; ++kk) {
        int ra = am + mf * 16 + l16;
        af[mf][kk] = *(const bf16x8*)(Ab + ra * 128 +
                                      (((kk * 4 + quad) ^ (ra & 7)) << 4));
      }
#pragma unroll
    for (int nf = 0; nf < 2; ++nf)
#pragma unroll
      for (int kk = 0; kk < 2; ++kk) {
        int rn = bn + nf * 16 + l16;
        bfr[nf][kk] = *(const bf16x8*)(Bb + rn * 128 +
                                       (((kk * 4 + quad) ^ (rn & 7)) << 4));
      }
    if (pf) stage(g + 1, wb, 0, 2);
    __builtin_amdgcn_s_barrier();
    __builtin_amdgcn_sched_barrier(0);
    __builtin_amdgcn_s_setprio(1);
#pragma unroll
    for (int kk = 0; kk < 2; ++kk)
#pragma unroll
      for (int mf = 0; mf < 4; ++mf)
#pragma unroll
        for (int nf = 0; nf < 2; ++nf)
          acc[mf][nf] = __builtin_amdgcn_mfma_f32_16x16x32_bf16(
              af[mf][kk], bfr[nf][kk], acc[mf][nf], 0, 0, 0);
    __builtin_amdgcn_s_setprio(0);
    __builtin_amdgcn_sched_barrier(0);
    __builtin_amdgcn_s_barrier();

    // ---- P1: ds_read B(nf2-3)x2kk (4 reads); stage u2-3 ----
#pragma unroll
    for (int nf = 2; nf < 4; ++nf)
#pragma unroll
      for (int kk = 0; kk < 2; ++kk) {
        int rn = bn + nf * 16 + l16;
        bfr[nf][kk] = *(const bf16x8*)(Bb + rn * 128 +
                                       (((kk * 4 + quad) ^ (rn & 7)) << 4));
      }
    if (pf) stage(g + 1, wb, 2, 4);
    __builtin_amdgcn_s_barrier();
    __builtin_amdgcn_sched_barrier(0);
    __builtin_amdgcn_s_setprio(1);
#pragma unroll
    for (int kk = 0; kk < 2; ++kk)
#pragma unroll
      for (int mf = 0; mf < 4; ++mf)
#pragma unroll
        for (int nf = 2; nf < 4; ++nf)
          acc[mf][nf] = __builtin_amdgcn_mfma_f32_16x16x32_bf16(
              af[mf][kk], bfr[nf][kk], acc[mf][nf], 0, 0, 0);
    __builtin_amdgcn_s_setprio(0);
    __builtin_amdgcn_sched_barrier(0);
    __builtin_amdgcn_s_barrier();

    // ---- P2: ds_read A(mf4-7)x2kk (8 reads, af reused); MFMA mf4-7 x nf2-3
#pragma unroll
    for (int mf = 0; mf < 4; ++mf)
#pragma unroll
      for (int kk = 0; kk < 2; ++kk) {
        int ra = am + 64 + mf * 16 + l16;
        af[mf][kk] = *(const bf16x8*)(Ab + ra * 128 +
                                      (((kk * 4 + quad) ^ (ra & 7)) << 4));
      }
    __builtin_amdgcn_s_barrier();
    __builtin_amdgcn_sched_barrier(0);
    __builtin_amdgcn_s_setprio(1);
#pragma unroll
    for (int kk = 0; kk < 2; ++kk)
#pragma unroll
      for (int mf = 0; mf < 4; ++mf)
#pragma unroll
        for (int nf = 2; nf < 4; ++nf)
          acc[mf + 4][nf] = __builtin_amdgcn_mfma_f32_16x16x32_bf16(
              af[mf][kk], bfr[nf][kk], acc[mf + 4][nf], 0, 0, 0);
    __builtin_amdgcn_s_setprio(0);
    __builtin_amdgcn_sched_barrier(0);
    __builtin_amdgcn_s_barrier();

    // ---- P3: MFMA mf4-7 x nf0-1 (no reads, no stage) ----
    __builtin_amdgcn_s_setprio(1);
#pragma unroll
    for (int kk = 0; kk < 2; ++kk)
#pragma unroll
      for (int mf = 0; mf < 4; ++mf)
#pragma unroll
        for (int nf = 0; nf < 2; ++nf)
          acc[mf + 4][nf] = __builtin_amdgcn_mfma_f32_16x16x32_bf16(
              af[mf][kk], bfr[nf][kk], acc[mf + 4][nf], 0, 0, 0);
    __builtin_amdgcn_s_setprio(0);
    __builtin_amdgcn_sched_barrier(0);
    // ---- buffer swap: wait own staging loads, then all waves ----
    asm volatile("s_waitcnt vmcnt(0)" ::: "memory");
    __builtin_amdgcn_s_barrier();
  };

  for (int g2 = 0; g2 < NT; g2 += 2) {
    group(g2, 0);
    group(g2 + 1, 1);
  }
}

// ---------- fused QKV projection; writes head-major [B,Hn,S,HD] bf16 ----------
__global__ __launch_bounds__(512, 2) void qkv_gemm(
    const bf16_t* __restrict__ x, const bf16_t* __restrict__ Wq,
    const bf16_t* __restrict__ Wk, const bf16_t* __restrict__ Wv,
    bf16_t* __restrict__ qo, bf16_t* __restrict__ ko, bf16_t* __restrict__ vo) {
  __shared__ __align__(16) bf16_t As[2][256 * 64];
  __shared__ __align__(16) bf16_t Bs[2][256 * 64];
  const int n0g = blockIdx.x * 256;
  const int m0 = blockIdx.y * 256;
  const bf16_t* B;
  bf16_t* O;
  int Hn, n0;
  if (n0g < 2048)      { B = Wq; O = qo; Hn = 16; n0 = n0g; }
  else if (n0g < 2560) { B = Wk; O = ko; Hn = 4;  n0 = n0g - 2048; }
  else                 { B = Wv; O = vo; Hn = 4;  n0 = n0g - 2560; }
  f32x4 acc[8][4] = {};
  gemm256_loop(x, B, 2048, m0, n0, As, Bs, acc);
  const int lane = threadIdx.x & 63, wid = threadIdx.x >> 6;
  const int quad = lane >> 4, l16 = lane & 15;
  const int am = (wid >> 2) * 128, bn = (wid & 3) * 64;
#pragma unroll
  for (int mf = 0; mf < 8; ++mf)
#pragma unroll
    for (int nf = 0; nf < 4; ++nf)
#pragma unroll
      for (int r = 0; r < 4; ++r) {
        int gr = m0 + am + mf * 16 + quad * 4 + r;
        int gc = n0 + bn + nf * 16 + l16;
        int bb = gr >> 11, ss = gr & 2047, hh = gc >> 7, dd = gc & 127;
        O[(((size_t)bb * Hn + hh) * 2048 + ss) * 128 + dd] = (bf16_t)acc[mf][nf][r];
      }
}

// ---------- output projection: out = ctx(bf16) * Wo(bf16)^T, fp32 out --------
__global__ __launch_bounds__(512, 2) void out_gemm(const bf16_t* __restrict__ ctx,
                                                   const bf16_t* __restrict__ Wo,
                                                   float* __restrict__ out) {
  __shared__ __align__(16) bf16_t As[2][256 * 64];
  __shared__ __align__(16) bf16_t Bs[2][256 * 64];
  const int n0 = blockIdx.x * 256, m0 = blockIdx.y * 256;
  f32x4 acc[8][4] = {};
  gemm256_loop(ctx, Wo, 2048, m0, n0, As, Bs, acc);
  const int lane = threadIdx.x & 63, wid = threadIdx.x >> 6;
  const int quad = lane >> 4, l16 = lane & 15;
  const int am = (wid >> 2) * 128, bn = (wid & 3) * 64;
#pragma unroll
  for (int mf = 0; mf < 8; ++mf)
#pragma unroll
    for (int nf = 0; nf < 4; ++nf)
#pragma unroll
      for (int r = 0; r < 4; ++r) {
        int gr = m0 + am + mf * 16 + quad * 4 + r;
        int gc = n0 + bn + nf * 16 + l16;
        out[(size_t)gr * 2048 + gc] = acc[mf][nf][r];
      }
}

// ---------- merged RMSNorm + RoPE for q and k (in place), one wave per row ----
__global__ __launch_bounds__(256) void rmsnorm_rope_all(
    bf16_t* __restrict__ qx, bf16_t* __restrict__ kx,
    const float* __restrict__ qw, const float* __restrict__ kw,
    const float* __restrict__ cs, const float* __restrict__ sn, float qscale) {
  int blk = blockIdx.x;
  bf16_t* basep;
  const float* wgt;
  float outscale;
  int row;
  if (blk < 16384) { basep = qx; wgt = qw; outscale = qscale; row = blk * 4 + (threadIdx.x >> 6); }
  else { basep = kx; wgt = kw; outscale = 1.0f; row = (blk - 16384) * 4 + (threadIdx.x >> 6); }
  const int lane = threadIdx.x & 63;
  const int pos = row & 2047;
  bf16_t* p = basep + (size_t)row * 128;
  float v1 = (float)p[lane];
  float v2 = (float)p[lane + 64];
  float ss = v1 * v1 + v2 * v2;
#pragma unroll
  for (int m = 32; m; m >>= 1) ss += __shfl_xor(ss, m);
  float rr = rsqrtf(ss * (1.0f / 128.0f) + 1e-6f);
  float n1 = v1 * rr * wgt[lane];
  float n2 = v2 * rr * wgt[lane + 64];
  float c1 = cs[pos * 128 + lane],      s1 = sn[pos * 128 + lane];
  float c2 = cs[pos * 128 + lane + 64], s2 = sn[pos * 128 + lane + 64];
  p[lane]      = (bf16_t)((n1 * c1 - n2 * s1) * outscale);
  p[lane + 64] = (bf16_t)((n2 * c2 + n1 * s2) * outscale);
}

// ---------- V transpose: [BG,S,HD] -> [BG,HD,S] ----------
__global__ __launch_bounds__(256) void vtrans(const bf16_t* __restrict__ v,
                                              bf16_t* __restrict__ vt) {
  __shared__ bf16_t t[64][72];
  const int bg = blockIdx.z, t0 = blockIdx.x * 64, d0 = blockIdx.y * 64;
  const int tid = threadIdx.x;
  const int r = tid >> 3, c = (tid & 7) * 8;
  const bf16_t* src = v + ((size_t)bg * 2048 + t0) * 128 + d0;
#pragma unroll
  for (int it = 0; it < 2; ++it) {
    uint4 val = *(const uint4*)(src + (size_t)(r + it * 32) * 128 + c);
    *(uint4*)&t[r + it * 32][c] = val;
  }
  __syncthreads();
#pragma unroll
  for (int it = 0; it < 2; ++it) {
    int d = r + it * 32;
    bf16_t tmp[8];
#pragma unroll
    for (int j = 0; j < 8; ++j) tmp[j] = t[c + j][d];
    *(uint4*)(vt + ((size_t)bg * 128 + d0 + d) * 2048 + t0 + c) = *(uint4*)tmp;
  }
}

// ---------- flash attention: GQA head-merged, uniform blocks, transposed QK --
// Exact R9 structure (known 83us): block (qi,g,b) processes q-tiles
// {qi,127-qi} -> 33 iters flat; 16 q-rows x 4 heads; K-loop in 64-col tiles.
// S^T = K*Q^T (operand swap) -> packed bf16x4 8B P-writes + scalar lsum.
// P: XOR-swizzled ping-pong LDS, one barrier/iter. Fixed-base softmax
// (HD^-0.5*log2e folded into q scale).
__global__ __launch_bounds__(256) void attn_kernel(const bf16_t* __restrict__ q,
    const bf16_t* __restrict__ k, const bf16_t* __restrict__ vt,
    bf16_t* __restrict__ ctx) {
  __shared__ __align__(16) char Plds[2][4][2048];  // [pb][h][16 rows x 128B]
  __shared__ __align__(16) float lred[4][16][4];
  const int qi = blockIdx.x, g = blockIdx.y, b = blockIdx.z;
  const int tid = threadIdx.x, w = tid >> 6, lane = tid & 63;
  const int quad = lane >> 4, l16 = lane & 15;
  const bf16_t* kp = k + ((size_t)b * 4 + g) * 2048 * 128 +
                     (size_t)(w * 16 + l16) * 128 + quad * 8;
  const bf16_t* vp = vt + ((size_t)b * 4 + g) * 128 * 2048 +
                     (size_t)(w * 32 + l16) * 2048 + quad * 8;

#pragma unroll 1
  for (int ph = 0; ph < 2; ++ph) {
    const int qt = ph ? 127 - qi : qi;

    // Q A-fragments: 16 rows (m=l16) per head (64 VGPR)
    bf16x8 qf[4][4];
#pragma unroll
    for (int h = 0; h < 4; ++h)
#pragma unroll
      for (int kk = 0; kk < 4; ++kk)
        qf[h][kk] = *(const bf16x8*)(q +
            (((size_t)b * 16 + g * 4 + h) * 2048 + (size_t)qt * 16 + l16) * 128 +
            kk * 32 + quad * 8);

    f32x4 oacc[4][2] = {};
    float lsum[4] = {};
    const int nkt = (qt >> 2) + 1;
    for (int kt = 0; kt < nkt; ++kt) {
      // K fragments (A-operand of S^T: m = kcol w*16+l16), one fetch, 4 heads
      const bf16_t* kro = kp + (size_t)kt * 64 * 128;
      bf16x8 kf[4];
#pragma unroll
      for (int kk = 0; kk < 4; ++kk) kf[kk] = *(const bf16x8*)(kro + kk * 32);
      // V fragments (B-layout n=l16 -> d = w*32+nd*16+l16), used after barrier
      const bf16_t* vro = vp + (size_t)kt * 64;
      bf16x8 vf[2][2];
#pragma unroll
      for (int nd = 0; nd < 2; ++nd)
#pragma unroll
        for (int kkp = 0; kkp < 2; ++kkp)
          vf[nd][kkp] = *(const bf16x8*)(vro + (size_t)nd * 16 * 2048 + kkp * 32);

      // S^T = K Q^T: C row = kcol_local (quad*4+r), col = qrow_local (l16)
      f32x4 sacc[4] = {};
#pragma unroll
      for (int kk = 0; kk < 4; ++kk)
#pragma unroll
        for (int h = 0; h < 4; ++h)
          sacc[h] = __builtin_amdgcn_mfma_f32_16x16x32_bf16(kf[kk], qf[h][kk],
                                                            sacc[h], 0, 0, 0);
      if (kt == nkt - 1) {  // diagonal tile: mask kcol > qrow
        int kcol = kt * 64 + w * 16 + quad * 4;
        int qrow = qt * 16 + l16;
#pragma unroll
        for (int r = 0; r < 4; ++r)
          if (kcol + r > qrow)
#pragma unroll
            for (int h = 0; h < 4; ++h) sacc[h][r] = -1e30f;
      }

      // softmax numerator + packed 8B P-write (row = qrow l16, 4 consec kcols)
      const int pb = kt & 1;
      const int c0 = w * 2 + (quad >> 1);
      const int woff = l16 * 128 + ((c0 ^ (l16 & 7)) << 4) + ((quad & 1) << 3);
#pragma unroll
      for (int h = 0; h < 4; ++h) {
        float p0 = __builtin_amdgcn_exp2f(sacc[h][0]);
        float p1 = __builtin_amdgcn_exp2f(sacc[h][1]);
        float p2 = __builtin_amdgcn_exp2f(sacc[h][2]);
        float p3 = __builtin_amdgcn_exp2f(sacc[h][3]);
        lsum[h] += (p0 + p1) + (p2 + p3);
        bf16x4 pk;
        pk[0] = (bf16_t)p0; pk[1] = (bf16_t)p1; pk[2] = (bf16_t)p2; pk[3] = (bf16_t)p3;
        *(bf16x4*)(Plds[pb][h] + woff) = pk;
      }
      __syncthreads();  // the only barrier in the loop

      // O += P * V: A = P (m=qrow l16, k=kcol quad*8+j), B = V^T
#pragma unroll
      for (int kkp = 0; kkp < 2; ++kkp) {
        bf16x8 pf[4];
#pragma unroll
        for (int h = 0; h < 4; ++h)
          pf[h] = *(const bf16x8*)(Plds[pb][h] + l16 * 128 +
                                   (((kkp * 4 + quad) ^ (l16 & 7)) << 4));
#pragma unroll
        for (int nd = 0; nd < 2; ++nd)
#pragma unroll
          for (int h = 0; h < 4; ++h)
            oacc[h][nd] = __builtin_amdgcn_mfma_f32_16x16x32_bf16(
                pf[h], vf[nd][kkp], oacc[h][nd], 0, 0, 0);
      }
    }

    // row-sum: lane's lsum covers its 4 kcols at qrow=l16; reduce across quads
    // (lanes l16, l16+16, l16+32, l16+48) then across waves via LDS.
#pragma unroll
    for (int h = 0; h < 4; ++h) {
      float v = lsum[h];
      v += __shfl_xor(v, 16);
      v += __shfl_xor(v, 32);
      if (quad == 0) lred[h][l16][w] = v;
    }
    __syncthreads();
    // epilogue: oacc C-layout row = qrow_local quad*4+r, col = d_local l16
#pragma unroll
    for (int h = 0; h < 4; ++h)
#pragma unroll
      for (int r = 0; r < 4; ++r) {
        int row = quad * 4 + r;
        f32x4 t = *(const f32x4*)lred[h][row];
        float inv = 1.f / (t[0] + t[1] + t[2] + t[3]);
        int pos = qt * 16 + row;
        size_t base = (((size_t)b * 2048 + pos) * 16 + g * 4 + h) * 128;
#pragma unroll
        for (int nd = 0; nd < 2; ++nd)
          ctx[base + w * 32 + nd * 16 + l16] = (bf16_t)(oacc[h][nd][r] * inv);
      }
  }
}

extern "C" void kernel_launch(void* const* d_in, const int* in_sizes, int n_in,
                              void* d_out, int out_size, void* d_ws, size_t ws_size,
                              hipStream_t stream) {
  (void)in_sizes; (void)n_in; (void)out_size; (void)ws_size;
  const float* x    = (const float*)d_in[0];
  const float* cosp = (const float*)d_in[2];
  const float* sinp = (const float*)d_in[3];
  const float* Wq   = (const float*)d_in[4];
  const float* Wk   = (const float*)d_in[5];
  const float* Wv   = (const float*)d_in[6];
  const float* Wo   = (const float*)d_in[7];
  const float* qnw  = (const float*)d_in[8];
  const float* knw  = (const float*)d_in[9];
  float* out = (float*)d_out;

  char* ws = (char*)d_ws;
  bf16_t* qb  = (bf16_t*)(ws);               // 16777216 B
  bf16_t* kb  = (bf16_t*)(ws + 16777216);    //  4194304 B
  bf16_t* vb  = (bf16_t*)(ws + 20971520);    //  4194304 B
  bf16_t* vtb = (bf16_t*)(ws + 25165824);    //  4194304 B
  bf16_t* ctx = (bf16_t*)(ws + 29360128);    // 16777216 B
  bf16_t* xb  = (bf16_t*)(ws + 29360128);    // aliases ctx (dead before attn)
  bf16_t* wqb = (bf16_t*)(ws + 46137344);    //  8388608 B
  bf16_t* wob = (bf16_t*)(ws + 46137344);    // aliases wqb (cast after qkv)
  bf16_t* wkb = (bf16_t*)(ws + 54525952);    //  2097152 B
  bf16_t* wvb = (bf16_t*)(ws + 56623104);    //  2097152 B

  cast_all<<<7168, 256, 0, stream>>>(x, Wq, Wk, Wv, xb, wqb, wkb, wvb);
  qkv_gemm<<<dim3(12, 16), 512, 0, stream>>>(xb, wqb, wkb, wvb, qb, kb, vb);
  // q scale = HD^-0.5 * log2(e) folded for fixed-base exp2 softmax
  rmsnorm_rope_all<<<20480, 256, 0, stream>>>(qb, kb, qnw, knw, cosp, sinp,
                                              0.12751742902f);
  vtrans<<<dim3(32, 2, 8), 256, 0, stream>>>(vb, vtb);
  attn_kernel<<<dim3(64, 4, 2), 256, 0, stream>>>(qb, kb, vtb, ctx);
  cast_f32_bf16<<<2048, 256, 0, stream>>>(Wo, wob);
  out_gemm<<<dim3(8, 16), 512, 0, stream>>>(ctx, wob, out);
}

// Round 5
// 347.490 us; speedup vs baseline: 1.2844x; 1.0391x over previous
//
#include <hip/hip_runtime.h>
#include <hip/hip_bf16.h>

// GroupedQueryAttention: B=2,S=2048,D=2048,H=16,G=4,HD=128, causal, rmsnorm+rope.
// Inputs fp32; OUTPUT fp32. Internal compute bf16 MFMA / fp32 accumulate.
// R14: GEMM schedule fixed to TRUE counted-vmcnt (T4): stage regions of tile
// t+2 are issued one phase after the same region's reads for tile t complete
// (P1:R0, P2:R1, P3:R2 -> 7-phase issue-to-consume), swap waits vmcnt(8)
// (never 0 in steady state). R13 drained vmcnt(0) per K-tile = the known
// m97-killer; m218: counted-vs-drain0 is +38-73%. attn = frozen R9 (83us).
// ws (58.7 MB): qb | kb | vb | vtb | ctx(=xb alias) | wqb(=wob) | wkb | wvb

typedef __bf16 bf16_t;
using bf16x4 = __attribute__((ext_vector_type(4))) __bf16;
using bf16x8 = __attribute__((ext_vector_type(8))) __bf16;
using f32x4  = __attribute__((ext_vector_type(4))) float;

#define LDSCP16(gp, lp)                                                       \
  __builtin_amdgcn_global_load_lds(                                           \
      (__attribute__((address_space(1))) void*)(gp),                          \
      (__attribute__((address_space(3))) void*)(lp), 16, 0, 0)

// ---------- merged fp32 -> bf16 casts: x | Wq | Wk | Wv ----------
__global__ __launch_bounds__(256) void cast_all(
    const float* __restrict__ x, const float* __restrict__ wq,
    const float* __restrict__ wk, const float* __restrict__ wv,
    bf16_t* __restrict__ xb, bf16_t* __restrict__ wqb,
    bf16_t* __restrict__ wkb, bf16_t* __restrict__ wvb) {
  int blk = blockIdx.x;
  const float* s;
  bf16_t* d;
  size_t base;
  if (blk < 4096)      { s = x;  d = xb;  base = blk; }
  else if (blk < 6144) { s = wq; d = wqb; base = blk - 4096; }
  else if (blk < 6656) { s = wk; d = wkb; base = blk - 6144; }
  else                 { s = wv; d = wvb; base = blk - 6656; }
  size_t i = base * 256 + threadIdx.x;
  const float* g = s + i * 8;
  f32x4 u0 = *(const f32x4*)g;
  f32x4 u1 = *(const f32x4*)(g + 4);
  bf16x8 v;
  v[0] = (bf16_t)u0[0]; v[1] = (bf16_t)u0[1]; v[2] = (bf16_t)u0[2]; v[3] = (bf16_t)u0[3];
  v[4] = (bf16_t)u1[0]; v[5] = (bf16_t)u1[1]; v[6] = (bf16_t)u1[2]; v[7] = (bf16_t)u1[3];
  *(bf16x8*)(d + i * 8) = v;
}

// ---------- single fp32 -> bf16 cast (Wo, after qkv frees wqb) ----------
__global__ __launch_bounds__(256) void cast_f32_bf16(const float* __restrict__ src,
                                                     bf16_t* __restrict__ dst) {
  size_t i = (size_t)blockIdx.x * 256 + threadIdx.x;
  const float* g = src + i * 8;
  f32x4 u0 = *(const f32x4*)g;
  f32x4 u1 = *(const f32x4*)(g + 4);
  bf16x8 v;
  v[0] = (bf16_t)u0[0]; v[1] = (bf16_t)u0[1]; v[2] = (bf16_t)u0[2]; v[3] = (bf16_t)u0[3];
  v[4] = (bf16_t)u1[0]; v[5] = (bf16_t)u1[1]; v[6] = (bf16_t)u1[2]; v[7] = (bf16_t)u1[3];
  *(bf16x8*)(dst + i * 8) = v;
}

// ---------- 256x256-tile counted-vmcnt GEMM mainloop: C = A*B^T (bf16) ------
// 512 thr = 8 waves (2M x 4N), wave tile 128x64, BK=64, dbuf LDS 128KB.
// Phase-read regions per K-tile buffer:
//   R0 (read P0): A rows {0-63,128-191} + B rows {0-31,64-95,128-159,192-223}
//   R1 (read P1): B rows {32-63,96-127,160-191,224-255}
//   R2 (read P2): A rows {64-127,192-255}
// Group g (reads tile t=g in buf g&1) stages tile t+2 into the SAME buffer:
// R0 at P1, R1 at P2, R2 at P3 — each one phase after its region's reads for
// tile t finished (barrier-separated; no write-before-read race). Swap wait
// is vmcnt(8): only this group's 8 staging loads may remain in flight, so
// tile t+1 (staged last group) is fully landed. Drain vmcnt(0) only at tail.
__device__ __forceinline__ void gemm256_loop(const bf16_t* __restrict__ A,
                                             const bf16_t* __restrict__ B,
                                             int K, int m0, int n0,
                                             bf16_t (*As)[256 * 64],
                                             bf16_t (*Bs)[256 * 64],
                                             f32x4 (&acc)[8][4]) {
  const int tid = threadIdx.x;
  const int lane = tid & 63, wid = tid >> 6;
  const int quad = lane >> 4, l16 = lane & 15;
  const int am = (wid >> 2) * 128;   // wave's A-row base (2 M-halves)
  const int bn = (wid & 3) * 64;     // wave's B-row base (4 N-quarters)
  const int NT = K >> 6;

  // Stage an A-region (2 loads/thread): region rows r<64 -> r+off,
  // r>=64 -> r+64+off (off=0: R0_A, off=64: R2_A). Dest LDS stays linear in
  // (row,chunk); source chunk XOR-swizzled (matches frag-read swizzle).
  auto stageA = [&](int t, int wb, int off) {
#pragma unroll
    for (int u = 0; u < 2; ++u) {
      int i = u * 512 + tid;
      int r = i >> 3, ch = i & 7;
      int row = (r & 63) + ((r >> 6) << 7) + off;
      int sc = ch ^ (row & 7);
      LDSCP16(A + (size_t)(m0 + row) * K + (size_t)t * 64 + sc * 8,
              (bf16_t*)As[wb] + (size_t)row * 64 + ch * 8);
    }
  };
  // Stage a B-region (2 loads/thread): row = (r&31) + (r>>5)*64 + off
  // (off=0: R0_B, off=32: R1_B).
  auto stageB = [&](int t, int wb, int off) {
#pragma unroll
    for (int u = 0; u < 2; ++u) {
      int i = u * 512 + tid;
      int r = i >> 3, ch = i & 7;
      int row = (r & 31) + ((r >> 5) << 6) + off;
      int sc = ch ^ (row & 7);
      LDSCP16(B + (size_t)(n0 + row) * K + (size_t)t * 64 + sc * 8,
              (bf16_t*)Bs[wb] + (size_t)row * 64 + ch * 8);
    }
  };

  // prologue: tile0 -> buf0 (8 loads), tile1 -> buf1 (8 loads); wait tile0.
  stageA(0, 0, 0); stageB(0, 0, 0); stageB(0, 0, 32); stageA(0, 0, 64);
  stageA(1, 1, 0); stageB(1, 1, 0); stageB(1, 1, 32); stageA(1, 1, 64);
  asm volatile("s_waitcnt vmcnt(8)" ::: "memory");
  __builtin_amdgcn_s_barrier();

  bf16x8 af[4][2], bfr[4][2];

  auto group = [&](int g, const int rb) {
    const char* Ab = (const char*)As[rb];
    const char* Bb = (const char*)Bs[rb];
    const bool pf = (g + 2 < NT);

    // ---- P0: ds_read af[mf0-3] (8) + bfr[nf0-1] (4); no staging ----
#pragma unroll
    for (int mf = 0; mf < 4; ++mf)
#pragma unroll
      for (int kk = 0; kk < 2; ++kk) {
        int ra = am + mf * 16 + l16;
        af[mf][kk] = *(const bf16x8*)(Ab + ra * 128 +
                                      (((kk * 4 + quad) ^ (ra & 7)) << 4));
      }
#pragma unroll
    for (int nf = 0; nf < 2; ++nf)
#pragma unroll
      for (int kk = 0; kk < 2; ++kk) {
        int rn = bn + nf * 16 + l16;
        bfr[nf][kk] = *(const bf16x8*)(Bb + rn * 128 +
                                       (((kk * 4 + quad) ^ (rn & 7)) << 4));
      }
    __builtin_amdgcn_s_barrier();
    __builtin_amdgcn_sched_barrier(0);
    __builtin_amdgcn_s_setprio(1);
#pragma unroll
    for (int kk = 0; kk < 2; ++kk)
#pragma unroll
      for (int mf = 0; mf < 4; ++mf)
#pragma unroll
        for (int nf = 0; nf < 2; ++nf)
          acc[mf][nf] = __builtin_amdgcn_mfma_f32_16x16x32_bf16(
              af[mf][kk], bfr[nf][kk], acc[mf][nf], 0, 0, 0);
    __builtin_amdgcn_s_setprio(0);
    __builtin_amdgcn_sched_barrier(0);
    __builtin_amdgcn_s_barrier();
    __builtin_amdgcn_sched_barrier(0);

    // ---- P1: ds_read bfr[nf2-3] (4); stage R0(t+2) [A then B, 4 loads] ----
#pragma unroll
    for (int nf = 2; nf < 4; ++nf)
#pragma unroll
      for (int kk = 0; kk < 2; ++kk) {
        int rn = bn + nf * 16 + l16;
        bfr[nf][kk] = *(const bf16x8*)(Bb + rn * 128 +
                                       (((kk * 4 + quad) ^ (rn & 7)) << 4));
      }
    if (pf) { stageA(g + 2, rb, 0); stageB(g + 2, rb, 0); }
    __builtin_amdgcn_s_barrier();
    __builtin_amdgcn_sched_barrier(0);
    __builtin_amdgcn_s_setprio(1);
#pragma unroll
    for (int kk = 0; kk < 2; ++kk)
#pragma unroll
      for (int mf = 0; mf < 4; ++mf)
#pragma unroll
        for (int nf = 2; nf < 4; ++nf)
          acc[mf][nf] = __builtin_amdgcn_mfma_f32_16x16x32_bf16(
              af[mf][kk], bfr[nf][kk], acc[mf][nf], 0, 0, 0);
    __builtin_amdgcn_s_setprio(0);
    __builtin_amdgcn_sched_barrier(0);
    __builtin_amdgcn_s_barrier();
    __builtin_amdgcn_sched_barrier(0);

    // ---- P2: ds_read af[mf4-7] (8, regs reused); stage R1(t+2) ----
#pragma unroll
    for (int mf = 0; mf < 4; ++mf)
#pragma unroll
      for (int kk = 0; kk < 2; ++kk) {
        int ra = am + 64 + mf * 16 + l16;
        af[mf][kk] = *(const bf16x8*)(Ab + ra * 128 +
                                      (((kk * 4 + quad) ^ (ra & 7)) << 4));
      }
    if (pf) stageB(g + 2, rb, 32);
    __builtin_amdgcn_s_barrier();
    __builtin_amdgcn_sched_barrier(0);
    __builtin_amdgcn_s_setprio(1);
#pragma unroll
    for (int kk = 0; kk < 2; ++kk)
#pragma unroll
      for (int mf = 0; mf < 4; ++mf)
#pragma unroll
        for (int nf = 2; nf < 4; ++nf)
          acc[mf + 4][nf] = __builtin_amdgcn_mfma_f32_16x16x32_bf16(
              af[mf][kk], bfr[nf][kk], acc[mf + 4][nf], 0, 0, 0);
    __builtin_amdgcn_s_setprio(0);
    __builtin_amdgcn_sched_barrier(0);
    __builtin_amdgcn_s_barrier();
    __builtin_amdgcn_sched_barrier(0);

    // ---- P3: stage R2(t+2); MFMA mf4-7 x nf0-1 (register-only); swap ----
    if (pf) stageA(g + 2, rb, 64);
    __builtin_amdgcn_sched_barrier(0);
    __builtin_amdgcn_s_setprio(1);
#pragma unroll
    for (int kk = 0; kk < 2; ++kk)
#pragma unroll
      for (int mf = 0; mf < 4; ++mf)
#pragma unroll
        for (int nf = 0; nf < 2; ++nf)
          acc[mf + 4][nf] = __builtin_amdgcn_mfma_f32_16x16x32_bf16(
              af[mf][kk], bfr[nf][kk], acc[mf + 4][nf], 0, 0, 0);
    __builtin_amdgcn_s_setprio(0);
    __builtin_amdgcn_sched_barrier(0);
    // counted swap wait: this group's 8 staging loads may stay in flight;
    // everything older (tile t+1) has landed. Tail groups drain.
    if (g + 2 < NT)      asm volatile("s_waitcnt vmcnt(8)" ::: "memory");
    else if (g + 1 < NT) asm volatile("s_waitcnt vmcnt(0)" ::: "memory");
    __builtin_amdgcn_s_barrier();
  };

  for (int g2 = 0; g2 < NT; g2 += 2) {
    group(g2, 0);
    group(g2 + 1, 1);
  }
}

// ---------- fused QKV projection; writes head-major [B,Hn,S,HD] bf16 ----------
__global__ __launch_bounds__(512, 2) void qkv_gemm(
    const bf16_t* __restrict__ x, const bf16_t* __restrict__ Wq,
    const bf16_t* __restrict__ Wk, const bf16_t* __restrict__ Wv,
    bf16_t* __restrict__ qo, bf16_t* __restrict__ ko, bf16_t* __restrict__ vo) {
  __shared__ __align__(16) bf16_t As[2][256 * 64];
  __shared__ __align__(16) bf16_t Bs[2][256 * 64];
  const int n0g = blockIdx.x * 256;
  const int m0 = blockIdx.y * 256;
  const bf16_t* B;
  bf16_t* O;
  int Hn, n0;
  if (n0g < 2048)      { B = Wq; O = qo; Hn = 16; n0 = n0g; }
  else if (n0g < 2560) { B = Wk; O = ko; Hn = 4;  n0 = n0g - 2048; }
  else                 { B = Wv; O = vo; Hn = 4;  n0 = n0g - 2560; }
  f32x4 acc[8][4] = {};
  gemm256_loop(x, B, 2048, m0, n0, As, Bs, acc);
  const int lane = threadIdx.x & 63, wid = threadIdx.x >> 6;
  const int quad = lane >> 4, l16 = lane & 15;
  const int am = (wid >> 2) * 128, bn = (wid & 3) * 64;
#pragma unroll
  for (int mf = 0; mf < 8; ++mf)
#pragma unroll
    for (int nf = 0; nf < 4; ++nf)
#pragma unroll
      for (int r = 0; r < 4; ++r) {
        int gr = m0 + am + mf * 16 + quad * 4 + r;
        int gc = n0 + bn + nf * 16 + l16;
        int bb = gr >> 11, ss = gr & 2047, hh = gc >> 7, dd = gc & 127;
        O[(((size_t)bb * Hn + hh) * 2048 + ss) * 128 + dd] = (bf16_t)acc[mf][nf][r];
      }
}

// ---------- output projection: out = ctx(bf16) * Wo(bf16)^T, fp32 out --------
__global__ __launch_bounds__(512, 2) void out_gemm(const bf16_t* __restrict__ ctx,
                                                   const bf16_t* __restrict__ Wo,
                                                   float* __restrict__ out) {
  __shared__ __align__(16) bf16_t As[2][256 * 64];
  __shared__ __align__(16) bf16_t Bs[2][256 * 64];
  const int n0 = blockIdx.x * 256, m0 = blockIdx.y * 256;
  f32x4 acc[8][4] = {};
  gemm256_loop(ctx, Wo, 2048, m0, n0, As, Bs, acc);
  const int lane = threadIdx.x & 63, wid = threadIdx.x >> 6;
  const int quad = lane >> 4, l16 = lane & 15;
  const int am = (wid >> 2) * 128, bn = (wid & 3) * 64;
#pragma unroll
  for (int mf = 0; mf < 8; ++mf)
#pragma unroll
    for (int nf = 0; nf < 4; ++nf)
#pragma unroll
      for (int r = 0; r < 4; ++r) {
        int gr = m0 + am + mf * 16 + quad * 4 + r;
        int gc = n0 + bn + nf * 16 + l16;
        out[(size_t)gr * 2048 + gc] = acc[mf][nf][r];
      }
}

// ---------- merged RMSNorm + RoPE for q and k (in place), one wave per row ----
__global__ __launch_bounds__(256) void rmsnorm_rope_all(
    bf16_t* __restrict__ qx, bf16_t* __restrict__ kx,
    const float* __restrict__ qw, const float* __restrict__ kw,
    const float* __restrict__ cs, const float* __restrict__ sn, float qscale) {
  int blk = blockIdx.x;
  bf16_t* basep;
  const float* wgt;
  float outscale;
  int row;
  if (blk < 16384) { basep = qx; wgt = qw; outscale = qscale; row = blk * 4 + (threadIdx.x >> 6); }
  else { basep = kx; wgt = kw; outscale = 1.0f; row = (blk - 16384) * 4 + (threadIdx.x >> 6); }
  const int lane = threadIdx.x & 63;
  const int pos = row & 2047;
  bf16_t* p = basep + (size_t)row * 128;
  float v1 = (float)p[lane];
  float v2 = (float)p[lane + 64];
  float ss = v1 * v1 + v2 * v2;
#pragma unroll
  for (int m = 32; m; m >>= 1) ss += __shfl_xor(ss, m);
  float rr = rsqrtf(ss * (1.0f / 128.0f) + 1e-6f);
  float n1 = v1 * rr * wgt[lane];
  float n2 = v2 * rr * wgt[lane + 64];
  float c1 = cs[pos * 128 + lane],      s1 = sn[pos * 128 + lane];
  float c2 = cs[pos * 128 + lane + 64], s2 = sn[pos * 128 + lane + 64];
  p[lane]      = (bf16_t)((n1 * c1 - n2 * s1) * outscale);
  p[lane + 64] = (bf16_t)((n2 * c2 + n1 * s2) * outscale);
}

// ---------- V transpose: [BG,S,HD] -> [BG,HD,S] ----------
__global__ __launch_bounds__(256) void vtrans(const bf16_t* __restrict__ v,
                                              bf16_t* __restrict__ vt) {
  __shared__ bf16_t t[64][72];
  const int bg = blockIdx.z, t0 = blockIdx.x * 64, d0 = blockIdx.y * 64;
  const int tid = threadIdx.x;
  const int r = tid >> 3, c = (tid & 7) * 8;
  const bf16_t* src = v + ((size_t)bg * 2048 + t0) * 128 + d0;
#pragma unroll
  for (int it = 0; it < 2; ++it) {
    uint4 val = *(const uint4*)(src + (size_t)(r + it * 32) * 128 + c);
    *(uint4*)&t[r + it * 32][c] = val;
  }
  __syncthreads();
#pragma unroll
  for (int it = 0; it < 2; ++it) {
    int d = r + it * 32;
    bf16_t tmp[8];
#pragma unroll
    for (int j = 0; j < 8; ++j) tmp[j] = t[c + j][d];
    *(uint4*)(vt + ((size_t)bg * 128 + d0 + d) * 2048 + t0 + c) = *(uint4*)tmp;
  }
}

// ---------- flash attention: GQA head-merged, uniform blocks, transposed QK --
// Exact R9 structure (known 83us): block (qi,g,b) processes q-tiles
// {qi,127-qi} -> 33 iters flat; 16 q-rows x 4 heads; K-loop in 64-col tiles.
// S^T = K*Q^T (operand swap) -> packed bf16x4 8B P-writes + scalar lsum.
// P: XOR-swizzled ping-pong LDS, one barrier/iter. Fixed-base softmax
// (HD^-0.5*log2e folded into q scale).
__global__ __launch_bounds__(256) void attn_kernel(const bf16_t* __restrict__ q,
    const bf16_t* __restrict__ k, const bf16_t* __restrict__ vt,
    bf16_t* __restrict__ ctx) {
  __shared__ __align__(16) char Plds[2][4][2048];  // [pb][h][16 rows x 128B]
  __shared__ __align__(16) float lred[4][16][4];
  const int qi = blockIdx.x, g = blockIdx.y, b = blockIdx.z;
  const int tid = threadIdx.x, w = tid >> 6, lane = tid & 63;
  const int quad = lane >> 4, l16 = lane & 15;
  const bf16_t* kp = k + ((size_t)b * 4 + g) * 2048 * 128 +
                     (size_t)(w * 16 + l16) * 128 + quad * 8;
  const bf16_t* vp = vt + ((size_t)b * 4 + g) * 128 * 2048 +
                     (size_t)(w * 32 + l16) * 2048 + quad * 8;

#pragma unroll 1
  for (int ph = 0; ph < 2; ++ph) {
    const int qt = ph ? 127 - qi : qi;

    // Q A-fragments: 16 rows (m=l16) per head (64 VGPR)
    bf16x8 qf[4][4];
#pragma unroll
    for (int h = 0; h < 4; ++h)
#pragma unroll
      for (int kk = 0; kk < 4; ++kk)
        qf[h][kk] = *(const bf16x8*)(q +
            (((size_t)b * 16 + g * 4 + h) * 2048 + (size_t)qt * 16 + l16) * 128 +
            kk * 32 + quad * 8);

    f32x4 oacc[4][2] = {};
    float lsum[4] = {};
    const int nkt = (qt >> 2) + 1;
    for (int kt = 0; kt < nkt; ++kt) {
      // K fragments (A-operand of S^T: m = kcol w*16+l16), one fetch, 4 heads
      const bf16_t* kro = kp + (size_t)kt * 64 * 128;
      bf16x8 kf[4];
#pragma unroll
      for (int kk = 0; kk < 4; ++kk) kf[kk] = *(const bf16x8*)(kro + kk * 32);
      // V fragments (B-layout n=l16 -> d = w*32+nd*16+l16), used after barrier
      const bf16_t* vro = vp + (size_t)kt * 64;
      bf16x8 vf[2][2];
#pragma unroll
      for (int nd = 0; nd < 2; ++nd)
#pragma unroll
        for (int kkp = 0; kkp < 2; ++kkp)
          vf[nd][kkp] = *(const bf16x8*)(vro + (size_t)nd * 16 * 2048 + kkp * 32);

      // S^T = K Q^T: C row = kcol_local (quad*4+r), col = qrow_local (l16)
      f32x4 sacc[4] = {};
#pragma unroll
      for (int kk = 0; kk < 4; ++kk)
#pragma unroll
        for (int h = 0; h < 4; ++h)
          sacc[h] = __builtin_amdgcn_mfma_f32_16x16x32_bf16(kf[kk], qf[h][kk],
                                                            sacc[h], 0, 0, 0);
      if (kt == nkt - 1) {  // diagonal tile: mask kcol > qrow
        int kcol = kt * 64 + w * 16 + quad * 4;
        int qrow = qt * 16 + l16;
#pragma unroll
        for (int r = 0; r < 4; ++r)
          if (kcol + r > qrow)
#pragma unroll
            for (int h = 0; h < 4; ++h) sacc[h][r] = -1e30f;
      }

      // softmax numerator + packed 8B P-write (row = qrow l16, 4 consec kcols)
      const int pb = kt & 1;
      const int c0 = w * 2 + (quad >> 1);
      const int woff = l16 * 128 + ((c0 ^ (l16 & 7)) << 4) + ((quad & 1) << 3);
#pragma unroll
      for (int h = 0; h < 4; ++h) {
        float p0 = __builtin_amdgcn_exp2f(sacc[h][0]);
        float p1 = __builtin_amdgcn_exp2f(sacc[h][1]);
        float p2 = __builtin_amdgcn_exp2f(sacc[h][2]);
        float p3 = __builtin_amdgcn_exp2f(sacc[h][3]);
        lsum[h] += (p0 + p1) + (p2 + p3);
        bf16x4 pk;
        pk[0] = (bf16_t)p0; pk[1] = (bf16_t)p1; pk[2] = (bf16_t)p2; pk[3] = (bf16_t)p3;
        *(bf16x4*)(Plds[pb][h] + woff) = pk;
      }
      __syncthreads();  // the only barrier in the loop

      // O += P * V: A = P (m=qrow l16, k=kcol quad*8+j), B = V^T
#pragma unroll
      for (int kkp = 0; kkp < 2; ++kkp) {
        bf16x8 pf[4];
#pragma unroll
        for (int h = 0; h < 4; ++h)
          pf[h] = *(const bf16x8*)(Plds[pb][h] + l16 * 128 +
                                   (((kkp * 4 + quad) ^ (l16 & 7)) << 4));
#pragma unroll
        for (int nd = 0; nd < 2; ++nd)
#pragma unroll
          for (int h = 0; h < 4; ++h)
            oacc[h][nd] = __builtin_amdgcn_mfma_f32_16x16x32_bf16(
                pf[h], vf[nd][kkp], oacc[h][nd], 0, 0, 0);
      }
    }

    // row-sum: lane's lsum covers its 4 kcols at qrow=l16; reduce across quads
    // (lanes l16, l16+16, l16+32, l16+48) then across waves via LDS.
#pragma unroll
    for (int h = 0; h < 4; ++h) {
      float v = lsum[h];
      v += __shfl_xor(v, 16);
      v += __shfl_xor(v, 32);
      if (quad == 0) lred[h][l16][w] = v;
    }
    __syncthreads();
    // epilogue: oacc C-layout row = qrow_local quad*4+r, col = d_local l16
#pragma unroll
    for (int h = 0; h < 4; ++h)
#pragma unroll
      for (int r = 0; r < 4; ++r) {
        int row = quad * 4 + r;
        f32x4 t = *(const f32x4*)lred[h][row];
        float inv = 1.f / (t[0] + t[1] + t[2] + t[3]);
        int pos = qt * 16 + row;
        size_t base = (((size_t)b * 2048 + pos) * 16 + g * 4 + h) * 128;
#pragma unroll
        for (int nd = 0; nd < 2; ++nd)
          ctx[base + w * 32 + nd * 16 + l16] = (bf16_t)(oacc[h][nd][r] * inv);
      }
  }
}

extern "C" void kernel_launch(void* const* d_in, const int* in_sizes, int n_in,
                              void* d_out, int out_size, void* d_ws, size_t ws_size,
                              hipStream_t stream) {
  (void)in_sizes; (void)n_in; (void)out_size; (void)ws_size;
  const float* x    = (const float*)d_in[0];
  const float* cosp = (const float*)d_in[2];
  const float* sinp = (const float*)d_in[3];
  const float* Wq   = (const float*)d_in[4];
  const float* Wk   = (const float*)d_in[5];
  const float* Wv   = (const float*)d_in[6];
  const float* Wo   = (const float*)d_in[7];
  const float* qnw  = (const float*)d_in[8];
  const float* knw  = (const float*)d_in[9];
  float* out = (float*)d_out;

  char* ws = (char*)d_ws;
  bf16_t* qb  = (bf16_t*)(ws);               // 16777216 B
  bf16_t* kb  = (bf16_t*)(ws + 16777216);    //  4194304 B
  bf16_t* vb  = (bf16_t*)(ws + 20971520);    //  4194304 B
  bf16_t* vtb = (bf16_t*)(ws + 25165824);    //  4194304 B
  bf16_t* ctx = (bf16_t*)(ws + 29360128);    // 16777216 B
  bf16_t* xb  = (bf16_t*)(ws + 29360128);    // aliases ctx (dead before attn)
  bf16_t* wqb = (bf16_t*)(ws + 46137344);    //  8388608 B
  bf16_t* wob = (bf16_t*)(ws + 46137344);    // aliases wqb (cast after qkv)
  bf16_t* wkb = (bf16_t*)(ws + 54525952);    //  2097152 B
  bf16_t* wvb = (bf16_t*)(ws + 56623104);    //  2097152 B

  cast_all<<<7168, 256, 0, stream>>>(x, Wq, Wk, Wv, xb, wqb, wkb, wvb);
  qkv_gemm<<<dim3(12, 16), 512, 0, stream>>>(xb, wqb, wkb, wvb, qb, kb, vb);
  // q scale = HD^-0.5 * log2(e) folded for fixed-base exp2 softmax
  rmsnorm_rope_all<<<20480, 256, 0, stream>>>(qb, kb, qnw, knw, cosp, sinp,
                                              0.12751742902f);
  vtrans<<<dim3(32, 2, 8), 256, 0, stream>>>(vb, vtb);
  attn_kernel<<<dim3(64, 4, 2), 256, 0, stream>>>(qb, kb, vtb, ctx);
  cast_f32_bf16<<<2048, 256, 0, stream>>>(Wo, wob);
  out_gemm<<<dim3(8, 16), 512, 0, stream>>>(ctx, wob, out);
}

// Round 6
// 326.796 us; speedup vs baseline: 1.3657x; 1.0633x over previous
//
#include <hip/hip_runtime.h>
#include <hip/hip_bf16.h>

// GroupedQueryAttention: B=2,S=2048,D=2048,H=16,G=4,HD=128, causal, rmsnorm+rope.
// Inputs fp32; OUTPUT fp32. Internal compute bf16 MFMA / fp32 accumulate.
// R15: (a) out_gemm re-tiled 128x256 -> grid 256 blocks = all CUs busy (was 128
// blocks = half chip idle); 2-phase counted-vmcnt loop, wave tile 64x64.
// (b) rmsnorm+vtrans+Wo-cast fused into ONE kernel (7->5 launches, ~10us+ gap
// savings). qkv keeps R14 4-phase 256^2 counted loop; attn = frozen R9.
// ws (58.7 MB): qb | kb | vb | vtb | ctx(=xb alias) | wqb(=wob) | wkb | wvb

typedef __bf16 bf16_t;
using bf16x4 = __attribute__((ext_vector_type(4))) __bf16;
using bf16x8 = __attribute__((ext_vector_type(8))) __bf16;
using f32x4  = __attribute__((ext_vector_type(4))) float;

#define LDSCP16(gp, lp)                                                       \
  __builtin_amdgcn_global_load_lds(                                           \
      (__attribute__((address_space(1))) void*)(gp),                          \
      (__attribute__((address_space(3))) void*)(lp), 16, 0, 0)

// ---------- merged fp32 -> bf16 casts: x | Wq | Wk | Wv ----------
__global__ __launch_bounds__(256) void cast_all(
    const float* __restrict__ x, const float* __restrict__ wq,
    const float* __restrict__ wk, const float* __restrict__ wv,
    bf16_t* __restrict__ xb, bf16_t* __restrict__ wqb,
    bf16_t* __restrict__ wkb, bf16_t* __restrict__ wvb) {
  int blk = blockIdx.x;
  const float* s;
  bf16_t* d;
  size_t base;
  if (blk < 4096)      { s = x;  d = xb;  base = blk; }
  else if (blk < 6144) { s = wq; d = wqb; base = blk - 4096; }
  else if (blk < 6656) { s = wk; d = wkb; base = blk - 6144; }
  else                 { s = wv; d = wvb; base = blk - 6656; }
  size_t i = base * 256 + threadIdx.x;
  const float* g = s + i * 8;
  f32x4 u0 = *(const f32x4*)g;
  f32x4 u1 = *(const f32x4*)(g + 4);
  bf16x8 v;
  v[0] = (bf16_t)u0[0]; v[1] = (bf16_t)u0[1]; v[2] = (bf16_t)u0[2]; v[3] = (bf16_t)u0[3];
  v[4] = (bf16_t)u1[0]; v[5] = (bf16_t)u1[1]; v[6] = (bf16_t)u1[2]; v[7] = (bf16_t)u1[3];
  *(bf16x8*)(d + i * 8) = v;
}

// ---------- 256x256-tile counted-vmcnt GEMM mainloop (qkv): C = A*B^T -------
// 512 thr = 8 waves (2M x 4N), wave tile 128x64, BK=64, dbuf LDS 128KB.
// Regions: R0(read P0)=A{0-63,128-191}+B{0-31,64-95,128-159,192-223};
// R1(read P1)=B{32-63,96-127,160-191,224-255}; R2(read P2)=A{64-127,192-255}.
// Group g stages tile t+2 into its own buffer one phase after each region's
// reads complete (P1:R0, P2:R1, P3:R2). Swap waits vmcnt(8); drain at tail.
__device__ __forceinline__ void gemm256_loop(const bf16_t* __restrict__ A,
                                             const bf16_t* __restrict__ B,
                                             int K, int m0, int n0,
                                             bf16_t (*As)[256 * 64],
                                             bf16_t (*Bs)[256 * 64],
                                             f32x4 (&acc)[8][4]) {
  const int tid = threadIdx.x;
  const int lane = tid & 63, wid = tid >> 6;
  const int quad = lane >> 4, l16 = lane & 15;
  const int am = (wid >> 2) * 128;   // wave's A-row base (2 M-halves)
  const int bn = (wid & 3) * 64;     // wave's B-row base (4 N-quarters)
  const int NT = K >> 6;

  auto stageA = [&](int t, int wb, int off) {
#pragma unroll
    for (int u = 0; u < 2; ++u) {
      int i = u * 512 + tid;
      int r = i >> 3, ch = i & 7;
      int row = (r & 63) + ((r >> 6) << 7) + off;
      int sc = ch ^ (row & 7);
      LDSCP16(A + (size_t)(m0 + row) * K + (size_t)t * 64 + sc * 8,
              (bf16_t*)As[wb] + (size_t)row * 64 + ch * 8);
    }
  };
  auto stageB = [&](int t, int wb, int off) {
#pragma unroll
    for (int u = 0; u < 2; ++u) {
      int i = u * 512 + tid;
      int r = i >> 3, ch = i & 7;
      int row = (r & 31) + ((r >> 5) << 6) + off;
      int sc = ch ^ (row & 7);
      LDSCP16(B + (size_t)(n0 + row) * K + (size_t)t * 64 + sc * 8,
              (bf16_t*)Bs[wb] + (size_t)row * 64 + ch * 8);
    }
  };

  stageA(0, 0, 0); stageB(0, 0, 0); stageB(0, 0, 32); stageA(0, 0, 64);
  stageA(1, 1, 0); stageB(1, 1, 0); stageB(1, 1, 32); stageA(1, 1, 64);
  asm volatile("s_waitcnt vmcnt(8)" ::: "memory");
  __builtin_amdgcn_s_barrier();

  bf16x8 af[4][2], bfr[4][2];

  auto group = [&](int g, const int rb) {
    const char* Ab = (const char*)As[rb];
    const char* Bb = (const char*)Bs[rb];
    const bool pf = (g + 2 < NT);

    // ---- P0: ds_read af[mf0-3] (8) + bfr[nf0-1] (4); no staging ----
#pragma unroll
    for (int mf = 0; mf < 4; ++mf)
#pragma unroll
      for (int kk = 0; kk < 2; ++kk) {
        int ra = am + mf * 16 + l16;
        af[mf][kk] = *(const bf16x8*)(Ab + ra * 128 +
                                      (((kk * 4 + quad) ^ (ra & 7)) << 4));
      }
#pragma unroll
    for (int nf = 0; nf < 2; ++nf)
#pragma unroll
      for (int kk = 0; kk < 2; ++kk) {
        int rn = bn + nf * 16 + l16;
        bfr[nf][kk] = *(const bf16x8*)(Bb + rn * 128 +
                                       (((kk * 4 + quad) ^ (rn & 7)) << 4));
      }
    __builtin_amdgcn_s_barrier();
    __builtin_amdgcn_sched_barrier(0);
    __builtin_amdgcn_s_setprio(1);
#pragma unroll
    for (int kk = 0; kk < 2; ++kk)
#pragma unroll
      for (int mf = 0; mf < 4; ++mf)
#pragma unroll
        for (int nf = 0; nf < 2; ++nf)
          acc[mf][nf] = __builtin_amdgcn_mfma_f32_16x16x32_bf16(
              af[mf][kk], bfr[nf][kk], acc[mf][nf], 0, 0, 0);
    __builtin_amdgcn_s_setprio(0);
    __builtin_amdgcn_sched_barrier(0);
    __builtin_amdgcn_s_barrier();
    __builtin_amdgcn_sched_barrier(0);

    // ---- P1: ds_read bfr[nf2-3] (4); stage R0(t+2) ----
#pragma unroll
    for (int nf = 2; nf < 4; ++nf)
#pragma unroll
      for (int kk = 0; kk < 2; ++kk) {
        int rn = bn + nf * 16 + l16;
        bfr[nf][kk] = *(const bf16x8*)(Bb + rn * 128 +
                                       (((kk * 4 + quad) ^ (rn & 7)) << 4));
      }
    if (pf) { stageA(g + 2, rb, 0); stageB(g + 2, rb, 0); }
    __builtin_amdgcn_s_barrier();
    __builtin_amdgcn_sched_barrier(0);
    __builtin_amdgcn_s_setprio(1);
#pragma unroll
    for (int kk = 0; kk < 2; ++kk)
#pragma unroll
      for (int mf = 0; mf < 4; ++mf)
#pragma unroll
        for (int nf = 2; nf < 4; ++nf)
          acc[mf][nf] = __builtin_amdgcn_mfma_f32_16x16x32_bf16(
              af[mf][kk], bfr[nf][kk], acc[mf][nf], 0, 0, 0);
    __builtin_amdgcn_s_setprio(0);
    __builtin_amdgcn_sched_barrier(0);
    __builtin_amdgcn_s_barrier();
    __builtin_amdgcn_sched_barrier(0);

    // ---- P2: ds_read af[mf4-7] (8, regs reused); stage R1(t+2) ----
#pragma unroll
    for (int mf = 0; mf < 4; ++mf)
#pragma unroll
      for (int kk = 0; kk < 2; ++kk) {
        int ra = am + 64 + mf * 16 + l16;
        af[mf][kk] = *(const bf16x8*)(Ab + ra * 128 +
                                      (((kk * 4 + quad) ^ (ra & 7)) << 4));
      }
    if (pf) stageB(g + 2, rb, 32);
    __builtin_amdgcn_s_barrier();
    __builtin_amdgcn_sched_barrier(0);
    __builtin_amdgcn_s_setprio(1);
#pragma unroll
    for (int kk = 0; kk < 2; ++kk)
#pragma unroll
      for (int mf = 0; mf < 4; ++mf)
#pragma unroll
        for (int nf = 2; nf < 4; ++nf)
          acc[mf + 4][nf] = __builtin_amdgcn_mfma_f32_16x16x32_bf16(
              af[mf][kk], bfr[nf][kk], acc[mf + 4][nf], 0, 0, 0);
    __builtin_amdgcn_s_setprio(0);
    __builtin_amdgcn_sched_barrier(0);
    __builtin_amdgcn_s_barrier();
    __builtin_amdgcn_sched_barrier(0);

    // ---- P3: stage R2(t+2); MFMA mf4-7 x nf0-1 (register-only); swap ----
    if (pf) stageA(g + 2, rb, 64);
    __builtin_amdgcn_sched_barrier(0);
    __builtin_amdgcn_s_setprio(1);
#pragma unroll
    for (int kk = 0; kk < 2; ++kk)
#pragma unroll
      for (int mf = 0; mf < 4; ++mf)
#pragma unroll
        for (int nf = 0; nf < 2; ++nf)
          acc[mf + 4][nf] = __builtin_amdgcn_mfma_f32_16x16x32_bf16(
              af[mf][kk], bfr[nf][kk], acc[mf + 4][nf], 0, 0, 0);
    __builtin_amdgcn_s_setprio(0);
    __builtin_amdgcn_sched_barrier(0);
    if (g + 2 < NT)      asm volatile("s_waitcnt vmcnt(8)" ::: "memory");
    else if (g + 1 < NT) asm volatile("s_waitcnt vmcnt(0)" ::: "memory");
    __builtin_amdgcn_s_barrier();
  };

  for (int g2 = 0; g2 < NT; g2 += 2) {
    group(g2, 0);
    group(g2 + 1, 1);
  }
}

// ---------- fused QKV projection; writes head-major [B,Hn,S,HD] bf16 ----------
__global__ __launch_bounds__(512, 2) void qkv_gemm(
    const bf16_t* __restrict__ x, const bf16_t* __restrict__ Wq,
    const bf16_t* __restrict__ Wk, const bf16_t* __restrict__ Wv,
    bf16_t* __restrict__ qo, bf16_t* __restrict__ ko, bf16_t* __restrict__ vo) {
  __shared__ __align__(16) bf16_t As[2][256 * 64];
  __shared__ __align__(16) bf16_t Bs[2][256 * 64];
  const int n0g = blockIdx.x * 256;
  const int m0 = blockIdx.y * 256;
  const bf16_t* B;
  bf16_t* O;
  int Hn, n0;
  if (n0g < 2048)      { B = Wq; O = qo; Hn = 16; n0 = n0g; }
  else if (n0g < 2560) { B = Wk; O = ko; Hn = 4;  n0 = n0g - 2048; }
  else                 { B = Wv; O = vo; Hn = 4;  n0 = n0g - 2560; }
  f32x4 acc[8][4] = {};
  gemm256_loop(x, B, 2048, m0, n0, As, Bs, acc);
  const int lane = threadIdx.x & 63, wid = threadIdx.x >> 6;
  const int quad = lane >> 4, l16 = lane & 15;
  const int am = (wid >> 2) * 128, bn = (wid & 3) * 64;
#pragma unroll
  for (int mf = 0; mf < 8; ++mf)
#pragma unroll
    for (int nf = 0; nf < 4; ++nf)
#pragma unroll
      for (int r = 0; r < 4; ++r) {
        int gr = m0 + am + mf * 16 + quad * 4 + r;
        int gc = n0 + bn + nf * 16 + l16;
        int bb = gr >> 11, ss = gr & 2047, hh = gc >> 7, dd = gc & 127;
        O[(((size_t)bb * Hn + hh) * 2048 + ss) * 128 + dd] = (bf16_t)acc[mf][nf][r];
      }
}

// ---------- 128x256-tile counted-vmcnt loop (out): full-chip grid ----------
// 512 thr = 8 waves (2M x 4N), wave tile 64x64, BK=64, dbuf LDS 96KB.
// Regions: A (all, read P0), B0=B{0-31,64-95,128-159,192-223} (read P0),
// B1=B{32-63,96-127,160-191,224-255} (read P1). Group g stages tile t+2:
// A+B0 at P1 (after P0 barrier), B1 after post-P1 barrier (all waves' P1
// MFMAs issued => B1 reads complete). Swap waits vmcnt(6); drain at tail.
__device__ __forceinline__ void gemm128x256_loop(const bf16_t* __restrict__ A,
                                                 const bf16_t* __restrict__ B,
                                                 int K, int m0, int n0,
                                                 bf16_t (*As)[128 * 64],
                                                 bf16_t (*Bs)[256 * 64],
                                                 f32x4 (&acc)[4][4]) {
  const int tid = threadIdx.x;
  const int lane = tid & 63, wid = tid >> 6;
  const int quad = lane >> 4, l16 = lane & 15;
  const int am = (wid >> 2) * 64;    // 2 M-halves of 64
  const int bn = (wid & 3) * 64;     // 4 N-quarters of 64
  const int NT = K >> 6;

  auto stageA = [&](int t, int wb) {
#pragma unroll
    for (int u = 0; u < 2; ++u) {
      int i = u * 512 + tid;
      int r = i >> 3, ch = i & 7;
      int sc = ch ^ (r & 7);
      LDSCP16(A + (size_t)(m0 + r) * K + (size_t)t * 64 + sc * 8,
              (bf16_t*)As[wb] + (size_t)r * 64 + ch * 8);
    }
  };
  auto stageB = [&](int t, int wb, int off) {
#pragma unroll
    for (int u = 0; u < 2; ++u) {
      int i = u * 512 + tid;
      int r = i >> 3, ch = i & 7;
      int row = (r & 31) + ((r >> 5) << 6) + off;
      int sc = ch ^ (row & 7);
      LDSCP16(B + (size_t)(n0 + row) * K + (size_t)t * 64 + sc * 8,
              (bf16_t*)Bs[wb] + (size_t)row * 64 + ch * 8);
    }
  };

  // prologue: tile0 -> buf0, tile1 -> buf1 (6 loads each); wait tile0.
  stageA(0, 0); stageB(0, 0, 0); stageB(0, 0, 32);
  stageA(1, 1); stageB(1, 1, 0); stageB(1, 1, 32);
  asm volatile("s_waitcnt vmcnt(6)" ::: "memory");
  __builtin_amdgcn_s_barrier();

  bf16x8 af[4][2], bfr[4][2];

  auto group = [&](int g, const int rb) {
    const char* Ab = (const char*)As[rb];
    const char* Bb = (const char*)Bs[rb];
    const bool pf = (g + 2 < NT);

    // ---- P0: ds_read af (8) + bfr[nf0-1] (4) ----
#pragma unroll
    for (int mf = 0; mf < 4; ++mf)
#pragma unroll
      for (int kk = 0; kk < 2; ++kk) {
        int ra = am + mf * 16 + l16;
        af[mf][kk] = *(const bf16x8*)(Ab + ra * 128 +
                                      (((kk * 4 + quad) ^ (ra & 7)) << 4));
      }
#pragma unroll
    for (int nf = 0; nf < 2; ++nf)
#pragma unroll
      for (int kk = 0; kk < 2; ++kk) {
        int rn = bn + nf * 16 + l16;
        bfr[nf][kk] = *(const bf16x8*)(Bb + rn * 128 +
                                       (((kk * 4 + quad) ^ (rn & 7)) << 4));
      }
    __builtin_amdgcn_s_barrier();
    __builtin_amdgcn_sched_barrier(0);
    __builtin_amdgcn_s_setprio(1);
#pragma unroll
    for (int kk = 0; kk < 2; ++kk)
#pragma unroll
      for (int mf = 0; mf < 4; ++mf)
#pragma unroll
        for (int nf = 0; nf < 2; ++nf)
          acc[mf][nf] = __builtin_amdgcn_mfma_f32_16x16x32_bf16(
              af[mf][kk], bfr[nf][kk], acc[mf][nf], 0, 0, 0);
    __builtin_amdgcn_s_setprio(0);
    __builtin_amdgcn_sched_barrier(0);
    __builtin_amdgcn_s_barrier();
    __builtin_amdgcn_sched_barrier(0);

    // ---- P1: ds_read bfr[nf2-3] (4); stage A(t+2)+B0(t+2) ----
#pragma unroll
    for (int nf = 2; nf < 4; ++nf)
#pragma unroll
      for (int kk = 0; kk < 2; ++kk) {
        int rn = bn + nf * 16 + l16;
        bfr[nf][kk] = *(const bf16x8*)(Bb + rn * 128 +
                                       (((kk * 4 + quad) ^ (rn & 7)) << 4));
      }
    if (pf) { stageA(g + 2, rb); stageB(g + 2, rb, 0); }
    __builtin_amdgcn_s_barrier();
    __builtin_amdgcn_sched_barrier(0);
    __builtin_amdgcn_s_setprio(1);
#pragma unroll
    for (int kk = 0; kk < 2; ++kk)
#pragma unroll
      for (int mf = 0; mf < 4; ++mf)
#pragma unroll
        for (int nf = 2; nf < 4; ++nf)
          acc[mf][nf] = __builtin_amdgcn_mfma_f32_16x16x32_bf16(
              af[mf][kk], bfr[nf][kk], acc[mf][nf], 0, 0, 0);
    __builtin_amdgcn_s_setprio(0);
    __builtin_amdgcn_sched_barrier(0);
    __builtin_amdgcn_s_barrier();   // all waves' P1 MFMAs issued => B1 reads done
    __builtin_amdgcn_sched_barrier(0);

    // ---- tail: stage B1(t+2); counted swap wait ----
    if (pf) stageB(g + 2, rb, 32);
    __builtin_amdgcn_sched_barrier(0);
    if (g + 2 < NT)      asm volatile("s_waitcnt vmcnt(6)" ::: "memory");
    else if (g + 1 < NT) asm volatile("s_waitcnt vmcnt(0)" ::: "memory");
    __builtin_amdgcn_s_barrier();
  };

  for (int g2 = 0; g2 < NT; g2 += 2) {
    group(g2, 0);
    group(g2 + 1, 1);
  }
}

// ---------- output projection: out = ctx(bf16) * Wo(bf16)^T, fp32 out --------
// grid (8,32) = 256 blocks -> every CU busy (was 128 with 256^2 tiles).
__global__ __launch_bounds__(512, 2) void out_gemm(const bf16_t* __restrict__ ctx,
                                                   const bf16_t* __restrict__ Wo,
                                                   float* __restrict__ out) {
  __shared__ __align__(16) bf16_t As[2][128 * 64];
  __shared__ __align__(16) bf16_t Bs[2][256 * 64];
  const int n0 = blockIdx.x * 256, m0 = blockIdx.y * 128;
  f32x4 acc[4][4] = {};
  gemm128x256_loop(ctx, Wo, 2048, m0, n0, As, Bs, acc);
  const int lane = threadIdx.x & 63, wid = threadIdx.x >> 6;
  const int quad = lane >> 4, l16 = lane & 15;
  const int am = (wid >> 2) * 64, bn = (wid & 3) * 64;
#pragma unroll
  for (int mf = 0; mf < 4; ++mf)
#pragma unroll
    for (int nf = 0; nf < 4; ++nf)
#pragma unroll
      for (int r = 0; r < 4; ++r) {
        int gr = m0 + am + mf * 16 + quad * 4 + r;
        int gc = n0 + bn + nf * 16 + l16;
        out[(size_t)gr * 2048 + gc] = acc[mf][nf][r];
      }
}

// ---------- fused mid-stage: RMSNorm+RoPE (q,k) | V transpose | Wo cast ------
// All three depend only on qkv_gemm; one launch instead of three.
// blocks [0,16384): q rows; [16384,20480): k rows; [20480,20992): vtrans;
// [20992,23040): Wo fp32->bf16 cast.
__global__ __launch_bounds__(256) void mid_fused(
    bf16_t* __restrict__ qx, bf16_t* __restrict__ kx,
    const float* __restrict__ qw, const float* __restrict__ kw,
    const float* __restrict__ cs, const float* __restrict__ sn, float qscale,
    const bf16_t* __restrict__ v, bf16_t* __restrict__ vt,
    const float* __restrict__ wo, bf16_t* __restrict__ wob) {
  __shared__ bf16_t t[64][72];
  const int blk = blockIdx.x;
  const int tid = threadIdx.x;
  if (blk < 20480) {
    // ---- RMSNorm + RoPE, one wave per row ----
    bf16_t* basep;
    const float* wgt;
    float outscale;
    int row;
    if (blk < 16384) { basep = qx; wgt = qw; outscale = qscale; row = blk * 4 + (tid >> 6); }
    else { basep = kx; wgt = kw; outscale = 1.0f; row = (blk - 16384) * 4 + (tid >> 6); }
    const int lane = tid & 63;
    const int pos = row & 2047;
    bf16_t* p = basep + (size_t)row * 128;
    float v1 = (float)p[lane];
    float v2 = (float)p[lane + 64];
    float ss = v1 * v1 + v2 * v2;
#pragma unroll
    for (int m = 32; m; m >>= 1) ss += __shfl_xor(ss, m);
    float rr = rsqrtf(ss * (1.0f / 128.0f) + 1e-6f);
    float n1 = v1 * rr * wgt[lane];
    float n2 = v2 * rr * wgt[lane + 64];
    float c1 = cs[pos * 128 + lane],      s1 = sn[pos * 128 + lane];
    float c2 = cs[pos * 128 + lane + 64], s2 = sn[pos * 128 + lane + 64];
    p[lane]      = (bf16_t)((n1 * c1 - n2 * s1) * outscale);
    p[lane + 64] = (bf16_t)((n2 * c2 + n1 * s2) * outscale);
  } else if (blk < 20992) {
    // ---- V transpose: [BG,S,HD] -> [BG,HD,S], 64x64 tile ----
    const int vv = blk - 20480;
    const int t0 = (vv & 31) * 64, d0 = ((vv >> 5) & 1) * 64, bg = vv >> 6;
    const int r = tid >> 3, c = (tid & 7) * 8;
    const bf16_t* src = v + ((size_t)bg * 2048 + t0) * 128 + d0;
#pragma unroll
    for (int it = 0; it < 2; ++it) {
      uint4 val = *(const uint4*)(src + (size_t)(r + it * 32) * 128 + c);
      *(uint4*)&t[r + it * 32][c] = val;
    }
    __syncthreads();
#pragma unroll
    for (int it = 0; it < 2; ++it) {
      int d = r + it * 32;
      bf16_t tmp[8];
#pragma unroll
      for (int j = 0; j < 8; ++j) tmp[j] = t[c + j][d];
      *(uint4*)(vt + ((size_t)bg * 128 + d0 + d) * 2048 + t0 + c) = *(uint4*)tmp;
    }
  } else {
    // ---- Wo fp32 -> bf16 ----
    size_t i = (size_t)(blk - 20992) * 256 + tid;
    const float* g = wo + i * 8;
    f32x4 u0 = *(const f32x4*)g;
    f32x4 u1 = *(const f32x4*)(g + 4);
    bf16x8 vv8;
    vv8[0] = (bf16_t)u0[0]; vv8[1] = (bf16_t)u0[1]; vv8[2] = (bf16_t)u0[2]; vv8[3] = (bf16_t)u0[3];
    vv8[4] = (bf16_t)u1[0]; vv8[5] = (bf16_t)u1[1]; vv8[6] = (bf16_t)u1[2]; vv8[7] = (bf16_t)u1[3];
    *(bf16x8*)(wob + i * 8) = vv8;
  }
}

// ---------- flash attention: GQA head-merged, uniform blocks, transposed QK --
// Exact R9 structure (known 83us): block (qi,g,b) processes q-tiles
// {qi,127-qi} -> 33 iters flat; 16 q-rows x 4 heads; K-loop in 64-col tiles.
// S^T = K*Q^T (operand swap) -> packed bf16x4 8B P-writes + scalar lsum.
// P: XOR-swizzled ping-pong LDS, one barrier/iter. Fixed-base softmax
// (HD^-0.5*log2e folded into q scale).
__global__ __launch_bounds__(256) void attn_kernel(const bf16_t* __restrict__ q,
    const bf16_t* __restrict__ k, const bf16_t* __restrict__ vt,
    bf16_t* __restrict__ ctx) {
  __shared__ __align__(16) char Plds[2][4][2048];  // [pb][h][16 rows x 128B]
  __shared__ __align__(16) float lred[4][16][4];
  const int qi = blockIdx.x, g = blockIdx.y, b = blockIdx.z;
  const int tid = threadIdx.x, w = tid >> 6, lane = tid & 63;
  const int quad = lane >> 4, l16 = lane & 15;
  const bf16_t* kp = k + ((size_t)b * 4 + g) * 2048 * 128 +
                     (size_t)(w * 16 + l16) * 128 + quad * 8;
  const bf16_t* vp = vt + ((size_t)b * 4 + g) * 128 * 2048 +
                     (size_t)(w * 32 + l16) * 2048 + quad * 8;

#pragma unroll 1
  for (int ph = 0; ph < 2; ++ph) {
    const int qt = ph ? 127 - qi : qi;

    // Q A-fragments: 16 rows (m=l16) per head (64 VGPR)
    bf16x8 qf[4][4];
#pragma unroll
    for (int h = 0; h < 4; ++h)
#pragma unroll
      for (int kk = 0; kk < 4; ++kk)
        qf[h][kk] = *(const bf16x8*)(q +
            (((size_t)b * 16 + g * 4 + h) * 2048 + (size_t)qt * 16 + l16) * 128 +
            kk * 32 + quad * 8);

    f32x4 oacc[4][2] = {};
    float lsum[4] = {};
    const int nkt = (qt >> 2) + 1;
    for (int kt = 0; kt < nkt; ++kt) {
      // K fragments (A-operand of S^T: m = kcol w*16+l16), one fetch, 4 heads
      const bf16_t* kro = kp + (size_t)kt * 64 * 128;
      bf16x8 kf[4];
#pragma unroll
      for (int kk = 0; kk < 4; ++kk) kf[kk] = *(const bf16x8*)(kro + kk * 32);
      // V fragments (B-layout n=l16 -> d = w*32+nd*16+l16), used after barrier
      const bf16_t* vro = vp + (size_t)kt * 64;
      bf16x8 vf[2][2];
#pragma unroll
      for (int nd = 0; nd < 2; ++nd)
#pragma unroll
        for (int kkp = 0; kkp < 2; ++kkp)
          vf[nd][kkp] = *(const bf16x8*)(vro + (size_t)nd * 16 * 2048 + kkp * 32);

      // S^T = K Q^T: C row = kcol_local (quad*4+r), col = qrow_local (l16)
      f32x4 sacc[4] = {};
#pragma unroll
      for (int kk = 0; kk < 4; ++kk)
#pragma unroll
        for (int h = 0; h < 4; ++h)
          sacc[h] = __builtin_amdgcn_mfma_f32_16x16x32_bf16(kf[kk], qf[h][kk],
                                                            sacc[h], 0, 0, 0);
      if (kt == nkt - 1) {  // diagonal tile: mask kcol > qrow
        int kcol = kt * 64 + w * 16 + quad * 4;
        int qrow = qt * 16 + l16;
#pragma unroll
        for (int r = 0; r < 4; ++r)
          if (kcol + r > qrow)
#pragma unroll
            for (int h = 0; h < 4; ++h) sacc[h][r] = -1e30f;
      }

      // softmax numerator + packed 8B P-write (row = qrow l16, 4 consec kcols)
      const int pb = kt & 1;
      const int c0 = w * 2 + (quad >> 1);
      const int woff = l16 * 128 + ((c0 ^ (l16 & 7)) << 4) + ((quad & 1) << 3);
#pragma unroll
      for (int h = 0; h < 4; ++h) {
        float p0 = __builtin_amdgcn_exp2f(sacc[h][0]);
        float p1 = __builtin_amdgcn_exp2f(sacc[h][1]);
        float p2 = __builtin_amdgcn_exp2f(sacc[h][2]);
        float p3 = __builtin_amdgcn_exp2f(sacc[h][3]);
        lsum[h] += (p0 + p1) + (p2 + p3);
        bf16x4 pk;
        pk[0] = (bf16_t)p0; pk[1] = (bf16_t)p1; pk[2] = (bf16_t)p2; pk[3] = (bf16_t)p3;
        *(bf16x4*)(Plds[pb][h] + woff) = pk;
      }
      __syncthreads();  // the only barrier in the loop

      // O += P * V: A = P (m=qrow l16, k=kcol quad*8+j), B = V^T
#pragma unroll
      for (int kkp = 0; kkp < 2; ++kkp) {
        bf16x8 pf[4];
#pragma unroll
        for (int h = 0; h < 4; ++h)
          pf[h] = *(const bf16x8*)(Plds[pb][h] + l16 * 128 +
                                   (((kkp * 4 + quad) ^ (l16 & 7)) << 4));
#pragma unroll
        for (int nd = 0; nd < 2; ++nd)
#pragma unroll
          for (int h = 0; h < 4; ++h)
            oacc[h][nd] = __builtin_amdgcn_mfma_f32_16x16x32_bf16(
                pf[h], vf[nd][kkp], oacc[h][nd], 0, 0, 0);
      }
    }

    // row-sum: lane's lsum covers its 4 kcols at qrow=l16; reduce across quads
    // (lanes l16, l16+16, l16+32, l16+48) then across waves via LDS.
#pragma unroll
    for (int h = 0; h < 4; ++h) {
      float v = lsum[h];
      v += __shfl_xor(v, 16);
      v += __shfl_xor(v, 32);
      if (quad == 0) lred[h][l16][w] = v;
    }
    __syncthreads();
    // epilogue: oacc C-layout row = qrow_local quad*4+r, col = d_local l16
#pragma unroll
    for (int h = 0; h < 4; ++h)
#pragma unroll
      for (int r = 0; r < 4; ++r) {
        int row = quad * 4 + r;
        f32x4 t = *(const f32x4*)lred[h][row];
        float inv = 1.f / (t[0] + t[1] + t[2] + t[3]);
        int pos = qt * 16 + row;
        size_t base = (((size_t)b * 2048 + pos) * 16 + g * 4 + h) * 128;
#pragma unroll
        for (int nd = 0; nd < 2; ++nd)
          ctx[base + w * 32 + nd * 16 + l16] = (bf16_t)(oacc[h][nd][r] * inv);
      }
  }
}

extern "C" void kernel_launch(void* const* d_in, const int* in_sizes, int n_in,
                              void* d_out, int out_size, void* d_ws, size_t ws_size,
                              hipStream_t stream) {
  (void)in_sizes; (void)n_in; (void)out_size; (void)ws_size;
  const float* x    = (const float*)d_in[0];
  const float* cosp = (const float*)d_in[2];
  const float* sinp = (const float*)d_in[3];
  const float* Wq   = (const float*)d_in[4];
  const float* Wk   = (const float*)d_in[5];
  const float* Wv   = (const float*)d_in[6];
  const float* Wo   = (const float*)d_in[7];
  const float* qnw  = (const float*)d_in[8];
  const float* knw  = (const float*)d_in[9];
  float* out = (float*)d_out;

  char* ws = (char*)d_ws;
  bf16_t* qb  = (bf16_t*)(ws);               // 16777216 B
  bf16_t* kb  = (bf16_t*)(ws + 16777216);    //  4194304 B
  bf16_t* vb  = (bf16_t*)(ws + 20971520);    //  4194304 B
  bf16_t* vtb = (bf16_t*)(ws + 25165824);    //  4194304 B
  bf16_t* ctx = (bf16_t*)(ws + 29360128);    // 16777216 B
  bf16_t* xb  = (bf16_t*)(ws + 29360128);    // aliases ctx (dead before attn)
  bf16_t* wqb = (bf16_t*)(ws + 46137344);    //  8388608 B
  bf16_t* wob = (bf16_t*)(ws + 46137344);    // aliases wqb (cast after qkv)
  bf16_t* wkb = (bf16_t*)(ws + 54525952);    //  2097152 B
  bf16_t* wvb = (bf16_t*)(ws + 56623104);    //  2097152 B

  cast_all<<<7168, 256, 0, stream>>>(x, Wq, Wk, Wv, xb, wqb, wkb, wvb);
  qkv_gemm<<<dim3(12, 16), 512, 0, stream>>>(xb, wqb, wkb, wvb, qb, kb, vb);
  // q scale = HD^-0.5 * log2(e) folded for fixed-base exp2 softmax
  mid_fused<<<23040, 256, 0, stream>>>(qb, kb, qnw, knw, cosp, sinp,
                                       0.12751742902f, vb, vtb, Wo, wob);
  attn_kernel<<<dim3(64, 4, 2), 256, 0, stream>>>(qb, kb, vtb, ctx);
  out_gemm<<<dim3(8, 32), 512, 0, stream>>>(ctx, wob, out);
}

// Round 9
// 325.760 us; speedup vs baseline: 1.3700x; 1.0032x over previous
//
#include <hip/hip_runtime.h>
#include <hip/hip_bf16.h>

// GroupedQueryAttention: B=2,S=2048,D=2048,H=16,G=4,HD=128, causal, rmsnorm+rope.
// Inputs fp32; OUTPUT fp32. Internal compute bf16 MFMA / fp32 accumulate.
// R18: revert attn to R15/R9 structure (K-parity split killed 2 container
// cycles — design space closed) + XCD-ownership remap: 1D grid 512, decode
// qi=bid>>3, gb=bid&7 -> dispatch RR gives each XCD exactly one (g,b) K/V
// stream (8MB) instead of all 8 (64MB) -> L2-resident K/V, lower load
// latency for this latency-bound kernel. Pure index remap, no sync changes.
// GEMMs/mid_fused = R15 verbatim (326.8us verified).
// ws (58.7 MB): qb | kb | vb | vtb | ctx(=xb alias) | wqb(=wob) | wkb | wvb

typedef __bf16 bf16_t;
using bf16x4 = __attribute__((ext_vector_type(4))) __bf16;
using bf16x8 = __attribute__((ext_vector_type(8))) __bf16;
using f32x4  = __attribute__((ext_vector_type(4))) float;

#define LDSCP16(gp, lp)                                                       \
  __builtin_amdgcn_global_load_lds(                                           \
      (__attribute__((address_space(1))) void*)(gp),                          \
      (__attribute__((address_space(3))) void*)(lp), 16, 0, 0)

// ---------- merged fp32 -> bf16 casts: x | Wq | Wk | Wv ----------
__global__ __launch_bounds__(256) void cast_all(
    const float* __restrict__ x, const float* __restrict__ wq,
    const float* __restrict__ wk, const float* __restrict__ wv,
    bf16_t* __restrict__ xb, bf16_t* __restrict__ wqb,
    bf16_t* __restrict__ wkb, bf16_t* __restrict__ wvb) {
  int blk = blockIdx.x;
  const float* s;
  bf16_t* d;
  size_t base;
  if (blk < 4096)      { s = x;  d = xb;  base = blk; }
  else if (blk < 6144) { s = wq; d = wqb; base = blk - 4096; }
  else if (blk < 6656) { s = wk; d = wkb; base = blk - 6144; }
  else                 { s = wv; d = wvb; base = blk - 6656; }
  size_t i = base * 256 + threadIdx.x;
  const float* g = s + i * 8;
  f32x4 u0 = *(const f32x4*)g;
  f32x4 u1 = *(const f32x4*)(g + 4);
  bf16x8 v;
  v[0] = (bf16_t)u0[0]; v[1] = (bf16_t)u0[1]; v[2] = (bf16_t)u0[2]; v[3] = (bf16_t)u0[3];
  v[4] = (bf16_t)u1[0]; v[5] = (bf16_t)u1[1]; v[6] = (bf16_t)u1[2]; v[7] = (bf16_t)u1[3];
  *(bf16x8*)(d + i * 8) = v;
}

// ---------- 256x256-tile counted-vmcnt GEMM mainloop (qkv): C = A*B^T -------
// 512 thr = 8 waves (2M x 4N), wave tile 128x64, BK=64, dbuf LDS 128KB.
// Regions: R0(read P0)=A{0-63,128-191}+B{0-31,64-95,128-159,192-223};
// R1(read P1)=B{32-63,96-127,160-191,224-255}; R2(read P2)=A{64-127,192-255}.
// Group g stages tile t+2 into its own buffer one phase after each region's
// reads complete (P1:R0, P2:R1, P3:R2). Swap waits vmcnt(8); drain at tail.
__device__ __forceinline__ void gemm256_loop(const bf16_t* __restrict__ A,
                                             const bf16_t* __restrict__ B,
                                             int K, int m0, int n0,
                                             bf16_t (*As)[256 * 64],
                                             bf16_t (*Bs)[256 * 64],
                                             f32x4 (&acc)[8][4]) {
  const int tid = threadIdx.x;
  const int lane = tid & 63, wid = tid >> 6;
  const int quad = lane >> 4, l16 = lane & 15;
  const int am = (wid >> 2) * 128;   // wave's A-row base (2 M-halves)
  const int bn = (wid & 3) * 64;     // wave's B-row base (4 N-quarters)
  const int NT = K >> 6;

  auto stageA = [&](int t, int wb, int off) {
#pragma unroll
    for (int i2 = 0; i2 < 2; ++i2) {
      int i = i2 * 512 + tid;
      int r = i >> 3, ch = i & 7;
      int row = (r & 63) + ((r >> 6) << 7) + off;
      int sc = ch ^ (row & 7);
      LDSCP16(A + (size_t)(m0 + row) * K + (size_t)t * 64 + sc * 8,
              (bf16_t*)As[wb] + (size_t)row * 64 + ch * 8);
    }
  };
  auto stageB = [&](int t, int wb, int off) {
#pragma unroll
    for (int i2 = 0; i2 < 2; ++i2) {
      int i = i2 * 512 + tid;
      int r = i >> 3, ch = i & 7;
      int row = (r & 31) + ((r >> 5) << 6) + off;
      int sc = ch ^ (row & 7);
      LDSCP16(B + (size_t)(n0 + row) * K + (size_t)t * 64 + sc * 8,
              (bf16_t*)Bs[wb] + (size_t)row * 64 + ch * 8);
    }
  };

  stageA(0, 0, 0); stageB(0, 0, 0); stageB(0, 0, 32); stageA(0, 0, 64);
  stageA(1, 1, 0); stageB(1, 1, 0); stageB(1, 1, 32); stageA(1, 1, 64);
  asm volatile("s_waitcnt vmcnt(8)" ::: "memory");
  __builtin_amdgcn_s_barrier();

  bf16x8 af[4][2], bfr[4][2];

  auto group = [&](int g, const int rb) {
    const char* Ab = (const char*)As[rb];
    const char* Bb = (const char*)Bs[rb];
    const bool pf = (g + 2 < NT);

    // ---- P0: ds_read af[mf0-3] (8) + bfr[nf0-1] (4); no staging ----
#pragma unroll
    for (int mf = 0; mf < 4; ++mf)
#pragma unroll
      for (int kk = 0; kk < 2; ++kk) {
        int ra = am + mf * 16 + l16;
        af[mf][kk] = *(const bf16x8*)(Ab + ra * 128 +
                                      (((kk * 4 + quad) ^ (ra & 7)) << 4));
      }
#pragma unroll
    for (int nf = 0; nf < 2; ++nf)
#pragma unroll
      for (int kk = 0; kk < 2; ++kk) {
        int rn = bn + nf * 16 + l16;
        bfr[nf][kk] = *(const bf16x8*)(Bb + rn * 128 +
                                       (((kk * 4 + quad) ^ (rn & 7)) << 4));
      }
    __builtin_amdgcn_s_barrier();
    __builtin_amdgcn_sched_barrier(0);
    __builtin_amdgcn_s_setprio(1);
#pragma unroll
    for (int kk = 0; kk < 2; ++kk)
#pragma unroll
      for (int mf = 0; mf < 4; ++mf)
#pragma unroll
        for (int nf = 0; nf < 2; ++nf)
          acc[mf][nf] = __builtin_amdgcn_mfma_f32_16x16x32_bf16(
              af[mf][kk], bfr[nf][kk], acc[mf][nf], 0, 0, 0);
    __builtin_amdgcn_s_setprio(0);
    __builtin_amdgcn_sched_barrier(0);
    __builtin_amdgcn_s_barrier();
    __builtin_amdgcn_sched_barrier(0);

    // ---- P1: ds_read bfr[nf2-3] (4); stage R0(t+2) ----
#pragma unroll
    for (int nf = 2; nf < 4; ++nf)
#pragma unroll
      for (int kk = 0; kk < 2; ++kk) {
        int rn = bn + nf * 16 + l16;
        bfr[nf][kk] = *(const bf16x8*)(Bb + rn * 128 +
                                       (((kk * 4 + quad) ^ (rn & 7)) << 4));
      }
    if (pf) { stageA(g + 2, rb, 0); stageB(g + 2, rb, 0); }
    __builtin_amdgcn_s_barrier();
    __builtin_amdgcn_sched_barrier(0);
    __builtin_amdgcn_s_setprio(1);
#pragma unroll
    for (int kk = 0; kk < 2; ++kk)
#pragma unroll
      for (int mf = 0; mf < 4; ++mf)
#pragma unroll
        for (int nf = 2; nf < 4; ++nf)
          acc[mf][nf] = __builtin_amdgcn_mfma_f32_16x16x32_bf16(
              af[mf][kk], bfr[nf][kk], acc[mf][nf], 0, 0, 0);
    __builtin_amdgcn_s_setprio(0);
    __builtin_amdgcn_sched_barrier(0);
    __builtin_amdgcn_s_barrier();
    __builtin_amdgcn_sched_barrier(0);

    // ---- P2: ds_read af[mf4-7] (8, regs reused); stage R1(t+2) ----
#pragma unroll
    for (int mf = 0; mf < 4; ++mf)
#pragma unroll
      for (int kk = 0; kk < 2; ++kk) {
        int ra = am + 64 + mf * 16 + l16;
        af[mf][kk] = *(const bf16x8*)(Ab + ra * 128 +
                                      (((kk * 4 + quad) ^ (ra & 7)) << 4));
      }
    if (pf) stageB(g + 2, rb, 32);
    __builtin_amdgcn_s_barrier();
    __builtin_amdgcn_sched_barrier(0);
    __builtin_amdgcn_s_setprio(1);
#pragma unroll
    for (int kk = 0; kk < 2; ++kk)
#pragma unroll
      for (int mf = 0; mf < 4; ++mf)
#pragma unroll
        for (int nf = 2; nf < 4; ++nf)
          acc[mf + 4][nf] = __builtin_amdgcn_mfma_f32_16x16x32_bf16(
              af[mf][kk], bfr[nf][kk], acc[mf + 4][nf], 0, 0, 0);
    __builtin_amdgcn_s_setprio(0);
    __builtin_amdgcn_sched_barrier(0);
    __builtin_amdgcn_s_barrier();
    __builtin_amdgcn_sched_barrier(0);

    // ---- P3: stage R2(t+2); MFMA mf4-7 x nf0-1 (register-only); swap ----
    if (pf) stageA(g + 2, rb, 64);
    __builtin_amdgcn_sched_barrier(0);
    __builtin_amdgcn_s_setprio(1);
#pragma unroll
    for (int kk = 0; kk < 2; ++kk)
#pragma unroll
      for (int mf = 0; mf < 4; ++mf)
#pragma unroll
        for (int nf = 0; nf < 2; ++nf)
          acc[mf + 4][nf] = __builtin_amdgcn_mfma_f32_16x16x32_bf16(
              af[mf][kk], bfr[nf][kk], acc[mf + 4][nf], 0, 0, 0);
    __builtin_amdgcn_s_setprio(0);
    __builtin_amdgcn_sched_barrier(0);
    if (g + 2 < NT)      asm volatile("s_waitcnt vmcnt(8)" ::: "memory");
    else if (g + 1 < NT) asm volatile("s_waitcnt vmcnt(0)" ::: "memory");
    __builtin_amdgcn_s_barrier();
  };

  for (int g2 = 0; g2 < NT; g2 += 2) {
    group(g2, 0);
    group(g2 + 1, 1);
  }
}

// ---------- fused QKV projection; writes head-major [B,Hn,S,HD] bf16 ----------
__global__ __launch_bounds__(512, 2) void qkv_gemm(
    const bf16_t* __restrict__ x, const bf16_t* __restrict__ Wq,
    const bf16_t* __restrict__ Wk, const bf16_t* __restrict__ Wv,
    bf16_t* __restrict__ qo, bf16_t* __restrict__ ko, bf16_t* __restrict__ vo) {
  __shared__ __align__(16) bf16_t As[2][256 * 64];
  __shared__ __align__(16) bf16_t Bs[2][256 * 64];
  const int n0g = blockIdx.x * 256;
  const int m0 = blockIdx.y * 256;
  const bf16_t* B;
  bf16_t* O;
  int Hn, n0;
  if (n0g < 2048)      { B = Wq; O = qo; Hn = 16; n0 = n0g; }
  else if (n0g < 2560) { B = Wk; O = ko; Hn = 4;  n0 = n0g - 2048; }
  else                 { B = Wv; O = vo; Hn = 4;  n0 = n0g - 2560; }
  f32x4 acc[8][4] = {};
  gemm256_loop(x, B, 2048, m0, n0, As, Bs, acc);
  const int lane = threadIdx.x & 63, wid = threadIdx.x >> 6;
  const int quad = lane >> 4, l16 = lane & 15;
  const int am = (wid >> 2) * 128, bn = (wid & 3) * 64;
#pragma unroll
  for (int mf = 0; mf < 8; ++mf)
#pragma unroll
    for (int nf = 0; nf < 4; ++nf)
#pragma unroll
      for (int r = 0; r < 4; ++r) {
        int gr = m0 + am + mf * 16 + quad * 4 + r;
        int gc = n0 + bn + nf * 16 + l16;
        int bb = gr >> 11, ss = gr & 2047, hh = gc >> 7, dd = gc & 127;
        O[(((size_t)bb * Hn + hh) * 2048 + ss) * 128 + dd] = (bf16_t)acc[mf][nf][r];
      }
}

// ---------- 128x256-tile counted-vmcnt loop (out): full-chip grid ----------
// 512 thr = 8 waves (2M x 4N), wave tile 64x64, BK=64, dbuf LDS 96KB.
// Regions: A+B0 (read P0), B1 (read P1). Group g stages tile t+2: A+B0 at P1,
// B1 after post-P1 barrier. Swap waits vmcnt(6); drain at tail.
__device__ __forceinline__ void gemm128x256_loop(const bf16_t* __restrict__ A,
                                                 const bf16_t* __restrict__ B,
                                                 int K, int m0, int n0,
                                                 bf16_t (*As)[128 * 64],
                                                 bf16_t (*Bs)[256 * 64],
                                                 f32x4 (&acc)[4][4]) {
  const int tid = threadIdx.x;
  const int lane = tid & 63, wid = tid >> 6;
  const int quad = lane >> 4, l16 = lane & 15;
  const int am = (wid >> 2) * 64;    // 2 M-halves of 64
  const int bn = (wid & 3) * 64;     // 4 N-quarters of 64
  const int NT = K >> 6;

  auto stageA = [&](int t, int wb) {
#pragma unroll
    for (int i2 = 0; i2 < 2; ++i2) {
      int i = i2 * 512 + tid;
      int r = i >> 3, ch = i & 7;
      int sc = ch ^ (r & 7);
      LDSCP16(A + (size_t)(m0 + r) * K + (size_t)t * 64 + sc * 8,
              (bf16_t*)As[wb] + (size_t)r * 64 + ch * 8);
    }
  };
  auto stageB = [&](int t, int wb, int off) {
#pragma unroll
    for (int i2 = 0; i2 < 2; ++i2) {
      int i = i2 * 512 + tid;
      int r = i >> 3, ch = i & 7;
      int row = (r & 31) + ((r >> 5) << 6) + off;
      int sc = ch ^ (row & 7);
      LDSCP16(B + (size_t)(n0 + row) * K + (size_t)t * 64 + sc * 8,
              (bf16_t*)Bs[wb] + (size_t)row * 64 + ch * 8);
    }
  };

  stageA(0, 0); stageB(0, 0, 0); stageB(0, 0, 32);
  stageA(1, 1); stageB(1, 1, 0); stageB(1, 1, 32);
  asm volatile("s_waitcnt vmcnt(6)" ::: "memory");
  __builtin_amdgcn_s_barrier();

  bf16x8 af[4][2], bfr[4][2];

  auto group = [&](int g, const int rb) {
    const char* Ab = (const char*)As[rb];
    const char* Bb = (const char*)Bs[rb];
    const bool pf = (g + 2 < NT);

    // ---- P0: ds_read af (8) + bfr[nf0-1] (4) ----
#pragma unroll
    for (int mf = 0; mf < 4; ++mf)
#pragma unroll
      for (int kk = 0; kk < 2; ++kk) {
        int ra = am + mf * 16 + l16;
        af[mf][kk] = *(const bf16x8*)(Ab + ra * 128 +
                                      (((kk * 4 + quad) ^ (ra & 7)) << 4));
      }
#pragma unroll
    for (int nf = 0; nf < 2; ++nf)
#pragma unroll
      for (int kk = 0; kk < 2; ++kk) {
        int rn = bn + nf * 16 + l16;
        bfr[nf][kk] = *(const bf16x8*)(Bb + rn * 128 +
                                       (((kk * 4 + quad) ^ (rn & 7)) << 4));
      }
    __builtin_amdgcn_s_barrier();
    __builtin_amdgcn_sched_barrier(0);
    __builtin_amdgcn_s_setprio(1);
#pragma unroll
    for (int kk = 0; kk < 2; ++kk)
#pragma unroll
      for (int mf = 0; mf < 4; ++mf)
#pragma unroll
        for (int nf = 0; nf < 2; ++nf)
          acc[mf][nf] = __builtin_amdgcn_mfma_f32_16x16x32_bf16(
              af[mf][kk], bfr[nf][kk], acc[mf][nf], 0, 0, 0);
    __builtin_amdgcn_s_setprio(0);
    __builtin_amdgcn_sched_barrier(0);
    __builtin_amdgcn_s_barrier();
    __builtin_amdgcn_sched_barrier(0);

    // ---- P1: ds_read bfr[nf2-3] (4); stage A(t+2)+B0(t+2) ----
#pragma unroll
    for (int nf = 2; nf < 4; ++nf)
#pragma unroll
      for (int kk = 0; kk < 2; ++kk) {
        int rn = bn + nf * 16 + l16;
        bfr[nf][kk] = *(const bf16x8*)(Bb + rn * 128 +
                                       (((kk * 4 + quad) ^ (rn & 7)) << 4));
      }
    if (pf) { stageA(g + 2, rb); stageB(g + 2, rb, 0); }
    __builtin_amdgcn_s_barrier();
    __builtin_amdgcn_sched_barrier(0);
    __builtin_amdgcn_s_setprio(1);
#pragma unroll
    for (int kk = 0; kk < 2; ++kk)
#pragma unroll
      for (int mf = 0; mf < 4; ++mf)
#pragma unroll
        for (int nf = 2; nf < 4; ++nf)
          acc[mf][nf] = __builtin_amdgcn_mfma_f32_16x16x32_bf16(
              af[mf][kk], bfr[nf][kk], acc[mf][nf], 0, 0, 0);
    __builtin_amdgcn_s_setprio(0);
    __builtin_amdgcn_sched_barrier(0);
    __builtin_amdgcn_s_barrier();   // all waves' P1 MFMAs issued => B1 reads done
    __builtin_amdgcn_sched_barrier(0);

    // ---- tail: stage B1(t+2); counted swap wait ----
    if (pf) stageB(g + 2, rb, 32);
    __builtin_amdgcn_sched_barrier(0);
    if (g + 2 < NT)      asm volatile("s_waitcnt vmcnt(6)" ::: "memory");
    else if (g + 1 < NT) asm volatile("s_waitcnt vmcnt(0)" ::: "memory");
    __builtin_amdgcn_s_barrier();
  };

  for (int g2 = 0; g2 < NT; g2 += 2) {
    group(g2, 0);
    group(g2 + 1, 1);
  }
}

// ---------- output projection: out = ctx(bf16) * Wo(bf16)^T, fp32 out --------
// grid (8,32) = 256 blocks -> every CU busy.
__global__ __launch_bounds__(512, 2) void out_gemm(const bf16_t* __restrict__ ctx,
                                                   const bf16_t* __restrict__ Wo,
                                                   float* __restrict__ out) {
  __shared__ __align__(16) bf16_t As[2][128 * 64];
  __shared__ __align__(16) bf16_t Bs[2][256 * 64];
  const int n0 = blockIdx.x * 256, m0 = blockIdx.y * 128;
  f32x4 acc[4][4] = {};
  gemm128x256_loop(ctx, Wo, 2048, m0, n0, As, Bs, acc);
  const int lane = threadIdx.x & 63, wid = threadIdx.x >> 6;
  const int quad = lane >> 4, l16 = lane & 15;
  const int am = (wid >> 2) * 64, bn = (wid & 3) * 64;
#pragma unroll
  for (int mf = 0; mf < 4; ++mf)
#pragma unroll
    for (int nf = 0; nf < 4; ++nf)
#pragma unroll
      for (int r = 0; r < 4; ++r) {
        int gr = m0 + am + mf * 16 + quad * 4 + r;
        int gc = n0 + bn + nf * 16 + l16;
        out[(size_t)gr * 2048 + gc] = acc[mf][nf][r];
      }
}

// ---------- fused mid-stage: RMSNorm+RoPE (q,k) | V transpose | Wo cast ------
// blocks [0,16384): q rows; [16384,20480): k rows; [20480,20992): vtrans;
// [20992,23040): Wo fp32->bf16 cast.
__global__ __launch_bounds__(256) void mid_fused(
    bf16_t* __restrict__ qx, bf16_t* __restrict__ kx,
    const float* __restrict__ qw, const float* __restrict__ kw,
    const float* __restrict__ cs, const float* __restrict__ sn, float qscale,
    const bf16_t* __restrict__ v, bf16_t* __restrict__ vt,
    const float* __restrict__ wo, bf16_t* __restrict__ wob) {
  __shared__ bf16_t t[64][72];
  const int blk = blockIdx.x;
  const int tid = threadIdx.x;
  if (blk < 20480) {
    // ---- RMSNorm + RoPE, one wave per row ----
    bf16_t* basep;
    const float* wgt;
    float outscale;
    int row;
    if (blk < 16384) { basep = qx; wgt = qw; outscale = qscale; row = blk * 4 + (tid >> 6); }
    else { basep = kx; wgt = kw; outscale = 1.0f; row = (blk - 16384) * 4 + (tid >> 6); }
    const int lane = tid & 63;
    const int pos = row & 2047;
    bf16_t* p = basep + (size_t)row * 128;
    float v1 = (float)p[lane];
    float v2 = (float)p[lane + 64];
    float ss = v1 * v1 + v2 * v2;
#pragma unroll
    for (int m = 32; m; m >>= 1) ss += __shfl_xor(ss, m);
    float rr = rsqrtf(ss * (1.0f / 128.0f) + 1e-6f);
    float n1 = v1 * rr * wgt[lane];
    float n2 = v2 * rr * wgt[lane + 64];
    float c1 = cs[pos * 128 + lane],      s1 = sn[pos * 128 + lane];
    float c2 = cs[pos * 128 + lane + 64], s2 = sn[pos * 128 + lane + 64];
    p[lane]      = (bf16_t)((n1 * c1 - n2 * s1) * outscale);
    p[lane + 64] = (bf16_t)((n2 * c2 + n1 * s2) * outscale);
  } else if (blk < 20992) {
    // ---- V transpose: [BG,S,HD] -> [BG,HD,S], 64x64 tile ----
    const int vv = blk - 20480;
    const int t0 = (vv & 31) * 64, d0 = ((vv >> 5) & 1) * 64, bg = vv >> 6;
    const int r = tid >> 3, c = (tid & 7) * 8;
    const bf16_t* src = v + ((size_t)bg * 2048 + t0) * 128 + d0;
#pragma unroll
    for (int it = 0; it < 2; ++it) {
      uint4 val = *(const uint4*)(src + (size_t)(r + it * 32) * 128 + c);
      *(uint4*)&t[r + it * 32][c] = val;
    }
    __syncthreads();
#pragma unroll
    for (int it = 0; it < 2; ++it) {
      int d = r + it * 32;
      bf16_t tmp[8];
#pragma unroll
      for (int j = 0; j < 8; ++j) tmp[j] = t[c + j][d];
      *(uint4*)(vt + ((size_t)bg * 128 + d0 + d) * 2048 + t0 + c) = *(uint4*)tmp;
    }
  } else {
    // ---- Wo fp32 -> bf16 ----
    size_t i = (size_t)(blk - 20992) * 256 + tid;
    const float* g = wo + i * 8;
    f32x4 u0 = *(const f32x4*)g;
    f32x4 u1 = *(const f32x4*)(g + 4);
    bf16x8 vv8;
    vv8[0] = (bf16_t)u0[0]; vv8[1] = (bf16_t)u0[1]; vv8[2] = (bf16_t)u0[2]; vv8[3] = (bf16_t)u0[3];
    vv8[4] = (bf16_t)u1[0]; vv8[5] = (bf16_t)u1[1]; vv8[6] = (bf16_t)u1[2]; vv8[7] = (bf16_t)u1[3];
    *(bf16x8*)(wob + i * 8) = vv8;
  }
}

// ---------- flash attention: GQA head-merged, uniform blocks, transposed QK --
// R9 structure (known-good) + XCD-ownership grid: 1D grid of 512 blocks,
// qi = bid>>3, gb = bid&7 (g=gb&3, b=gb>>2). Dispatch round-robin over 8 XCDs
// gives each XCD exactly one (g,b) -> its 64 blocks stream ONE 8MB K/V set
// through the 4MB L2 instead of eight. Block does q-tiles {qi,127-qi} (33
// iters, uniform). Per tile: 16 q-rows x 4 heads; K-loop in 64-col tiles.
// S^T = K*Q^T -> packed bf16x4 P-writes + scalar lsum; XOR-swizzled ping-pong
// P LDS, one barrier/iter. Fixed-base softmax (HD^-0.5*log2e in q scale).
__global__ __launch_bounds__(256) void attn_kernel(const bf16_t* __restrict__ q,
    const bf16_t* __restrict__ k, const bf16_t* __restrict__ vt,
    bf16_t* __restrict__ ctx) {
  __shared__ __align__(16) char Plds[2][4][2048];  // [pb][h][16 rows x 128B]
  __shared__ __align__(16) float lred[4][16][4];
  const int bid = blockIdx.x;
  const int qi = bid >> 3, gb = bid & 7;
  const int g = gb & 3, b = gb >> 2;
  const int tid = threadIdx.x, w = tid >> 6, lane = tid & 63;
  const int quad = lane >> 4, l16 = lane & 15;
  const bf16_t* kp = k + ((size_t)b * 4 + g) * 2048 * 128 +
                     (size_t)(w * 16 + l16) * 128 + quad * 8;
  const bf16_t* vp = vt + ((size_t)b * 4 + g) * 128 * 2048 +
                     (size_t)(w * 32 + l16) * 2048 + quad * 8;

#pragma unroll 1
  for (int ph = 0; ph < 2; ++ph) {
    const int qt = ph ? 127 - qi : qi;

    // Q A-fragments: 16 rows (m=l16) per head (64 VGPR)
    bf16x8 qf[4][4];
#pragma unroll
    for (int h = 0; h < 4; ++h)
#pragma unroll
      for (int kk = 0; kk < 4; ++kk)
        qf[h][kk] = *(const bf16x8*)(q +
            (((size_t)b * 16 + g * 4 + h) * 2048 + (size_t)qt * 16 + l16) * 128 +
            kk * 32 + quad * 8);

    f32x4 oacc[4][2] = {};
    float lsum[4] = {};
    const int nkt = (qt >> 2) + 1;
    for (int kt = 0; kt < nkt; ++kt) {
      // K fragments (A-operand of S^T: m = kcol w*16+l16), one fetch, 4 heads
      const bf16_t* kro = kp + (size_t)kt * 64 * 128;
      bf16x8 kf[4];
#pragma unroll
      for (int kk = 0; kk < 4; ++kk) kf[kk] = *(const bf16x8*)(kro + kk * 32);
      // V fragments (B-layout n=l16 -> d = w*32+nd*16+l16), used after barrier
      const bf16_t* vro = vp + (size_t)kt * 64;
      bf16x8 vf[2][2];
#pragma unroll
      for (int nd = 0; nd < 2; ++nd)
#pragma unroll
        for (int kkp = 0; kkp < 2; ++kkp)
          vf[nd][kkp] = *(const bf16x8*)(vro + (size_t)nd * 16 * 2048 + kkp * 32);

      // S^T = K Q^T: C row = kcol_local (quad*4+r), col = qrow_local (l16)
      f32x4 sacc[4] = {};
#pragma unroll
      for (int kk = 0; kk < 4; ++kk)
#pragma unroll
        for (int h = 0; h < 4; ++h)
          sacc[h] = __builtin_amdgcn_mfma_f32_16x16x32_bf16(kf[kk], qf[h][kk],
                                                            sacc[h], 0, 0, 0);
      if (kt == nkt - 1) {  // diagonal tile: mask kcol > qrow
        int kcol = kt * 64 + w * 16 + quad * 4;
        int qrow = qt * 16 + l16;
#pragma unroll
        for (int r = 0; r < 4; ++r)
          if (kcol + r > qrow)
#pragma unroll
            for (int h = 0; h < 4; ++h) sacc[h][r] = -1e30f;
      }

      // softmax numerator + packed 8B P-write (row = qrow l16, 4 consec kcols)
      const int pb = kt & 1;
      const int c0 = w * 2 + (quad >> 1);
      const int woff = l16 * 128 + ((c0 ^ (l16 & 7)) << 4) + ((quad & 1) << 3);
#pragma unroll
      for (int h = 0; h < 4; ++h) {
        float p0 = __builtin_amdgcn_exp2f(sacc[h][0]);
        float p1 = __builtin_amdgcn_exp2f(sacc[h][1]);
        float p2 = __builtin_amdgcn_exp2f(sacc[h][2]);
        float p3 = __builtin_amdgcn_exp2f(sacc[h][3]);
        lsum[h] += (p0 + p1) + (p2 + p3);
        bf16x4 pk;
        pk[0] = (bf16_t)p0; pk[1] = (bf16_t)p1; pk[2] = (bf16_t)p2; pk[3] = (bf16_t)p3;
        *(bf16x4*)(Plds[pb][h] + woff) = pk;
      }
      __syncthreads();  // the only barrier in the loop

      // O += P * V: A = P (m=qrow l16, k=kcol quad*8+j), B = V^T
#pragma unroll
      for (int kkp = 0; kkp < 2; ++kkp) {
        bf16x8 pf[4];
#pragma unroll
        for (int h = 0; h < 4; ++h)
          pf[h] = *(const bf16x8*)(Plds[pb][h] + l16 * 128 +
                                   (((kkp * 4 + quad) ^ (l16 & 7)) << 4));
#pragma unroll
        for (int nd = 0; nd < 2; ++nd)
#pragma unroll
          for (int h = 0; h < 4; ++h)
            oacc[h][nd] = __builtin_amdgcn_mfma_f32_16x16x32_bf16(
                pf[h], vf[nd][kkp], oacc[h][nd], 0, 0, 0);
      }
    }

    // row-sum: lane's lsum covers its 4 kcols at qrow=l16; reduce across quads
    // (lanes l16, l16+16, l16+32, l16+48) then across waves via LDS.
#pragma unroll
    for (int h = 0; h < 4; ++h) {
      float v = lsum[h];
      v += __shfl_xor(v, 16);
      v += __shfl_xor(v, 32);
      if (quad == 0) lred[h][l16][w] = v;
    }
    __syncthreads();
    // epilogue: oacc C-layout row = qrow_local quad*4+r, col = d_local l16
#pragma unroll
    for (int h = 0; h < 4; ++h)
#pragma unroll
      for (int r = 0; r < 4; ++r) {
        int row = quad * 4 + r;
        f32x4 t = *(const f32x4*)lred[h][row];
        float inv = 1.f / (t[0] + t[1] + t[2] + t[3]);
        int pos = qt * 16 + row;
        size_t base = (((size_t)b * 2048 + pos) * 16 + g * 4 + h) * 128;
#pragma unroll
        for (int nd = 0; nd < 2; ++nd)
          ctx[base + w * 32 + nd * 16 + l16] = (bf16_t)(oacc[h][nd][r] * inv);
      }
  }
}

extern "C" void kernel_launch(void* const* d_in, const int* in_sizes, int n_in,
                              void* d_out, int out_size, void* d_ws, size_t ws_size,
                              hipStream_t stream) {
  (void)in_sizes; (void)n_in; (void)out_size; (void)ws_size;
  const float* x    = (const float*)d_in[0];
  const float* cosp = (const float*)d_in[2];
  const float* sinp = (const float*)d_in[3];
  const float* Wq   = (const float*)d_in[4];
  const float* Wk   = (const float*)d_in[5];
  const float* Wv   = (const float*)d_in[6];
  const float* Wo   = (const float*)d_in[7];
  const float* qnw  = (const float*)d_in[8];
  const float* knw  = (const float*)d_in[9];
  float* out = (float*)d_out;

  char* ws = (char*)d_ws;
  bf16_t* qb  = (bf16_t*)(ws);               // 16777216 B
  bf16_t* kb  = (bf16_t*)(ws + 16777216);    //  4194304 B
  bf16_t* vb  = (bf16_t*)(ws + 20971520);    //  4194304 B
  bf16_t* vtb = (bf16_t*)(ws + 25165824);    //  4194304 B
  bf16_t* ctx = (bf16_t*)(ws + 29360128);    // 16777216 B
  bf16_t* xb  = (bf16_t*)(ws + 29360128);    // aliases ctx (dead before attn)
  bf16_t* wqb = (bf16_t*)(ws + 46137344);    //  8388608 B
  bf16_t* wob = (bf16_t*)(ws + 46137344);    // aliases wqb (cast after qkv)
  bf16_t* wkb = (bf16_t*)(ws + 54525952);    //  2097152 B
  bf16_t* wvb = (bf16_t*)(ws + 56623104);    //  2097152 B

  cast_all<<<7168, 256, 0, stream>>>(x, Wq, Wk, Wv, xb, wqb, wkb, wvb);
  qkv_gemm<<<dim3(12, 16), 512, 0, stream>>>(xb, wqb, wkb, wvb, qb, kb, vb);
  // q scale = HD^-0.5 * log2(e) folded for fixed-base exp2 softmax
  mid_fused<<<23040, 256, 0, stream>>>(qb, kb, qnw, knw, cosp, sinp,
                                       0.12751742902f, vb, vtb, Wo, wob);
  attn_kernel<<<512, 256, 0, stream>>>(qb, kb, vtb, ctx);
  out_gemm<<<dim3(8, 32), 512, 0, stream>>>(ctx, wob, out);
}